// Round 7
// baseline (12529.791 us; speedup 1.0000x reference)
//
#include <hip/hip_runtime.h>
#include <math.h>

#define SLEN 64
#define BATCH 256
#define VIND 128
#define VOUTD 128
#define UDIM 1024
#define EDIM 512
#define TDEC 25
#define GXW 1536
#define U3 3072
#define NBLK 256

typedef __attribute__((ext_vector_type(8))) short short8;
typedef __attribute__((ext_vector_type(4))) float f32x4;

#define MFMA(acc, A, B) acc = __builtin_amdgcn_mfma_f32_16x16x32_bf16((A), (B), (acc), 0, 0, 0)

__device__ __forceinline__ float sigm(float x) { return 1.f / (1.f + expf(-x)); }

__device__ __forceinline__ short f2bf(float f) {
    unsigned u = __float_as_uint(f);
    u += 0x7FFF + ((u >> 16) & 1);
    return (short)(u >> 16);
}
__device__ __forceinline__ float bf2f(short h) {
    return __uint_as_float(((unsigned)(unsigned short)h) << 16);
}

// fragment-major packed layout for operand X[R][K]:
// chunk(r,k) holds X[r][k..k+8); lane = (r&15) + 16*((k>>3)&3)
__device__ __forceinline__ size_t pkChunk(int r, int k, int K) {
    return ((size_t)(r >> 4) * (K >> 5) + (k >> 5)) * 64 + ((r & 15) + 16 * ((k >> 3) & 3));
}

union S8 { short s[8]; short8 v; };

__device__ __forceinline__ void writeSplit8(short* Hi, short* Lo, size_t chunk,
                                            const float* vals) {
    S8 h, l;
#pragma unroll
    for (int j = 0; j < 8; j++) {
        short hb = f2bf(vals[j]);
        h.s[j] = hb;
        l.s[j] = f2bf(vals[j] - bf2f(hb));
    }
    ((short8*)Hi)[chunk] = h.v;
    ((short8*)Lo)[chunk] = l.v;
}

// ---------------------------------------------------------------------------
// Grid barrier: sense via monotonically increasing generation counter.
// All 256 blocks co-resident (grid=256 blocks of 256 threads, >=1 block/CU).
// ---------------------------------------------------------------------------
__device__ __forceinline__ void gridBar(int* bar, int* gen, int& myGen) {
    __syncthreads();
    if (threadIdx.x == 0) {
        __threadfence();  // release: flush this XCD's L2
        int prev = __hip_atomic_fetch_add(bar, 1, __ATOMIC_ACQ_REL, __HIP_MEMORY_SCOPE_AGENT);
        if (prev == NBLK - 1) {
            __hip_atomic_store(bar, 0, __ATOMIC_RELAXED, __HIP_MEMORY_SCOPE_AGENT);
            __hip_atomic_fetch_add(gen, 1, __ATOMIC_ACQ_REL, __HIP_MEMORY_SCOPE_AGENT);
        } else {
            while (__hip_atomic_load(gen, __ATOMIC_ACQUIRE, __HIP_MEMORY_SCOPE_AGENT) <= myGen) {
                __builtin_amdgcn_s_sleep(4);
            }
        }
        __threadfence();  // acquire: invalidate so remote writes are visible
    }
    myGen++;
    __syncthreads();
}

// ---------------------------------------------------------------------------
__global__ void init_kernel(float* __restrict__ h0, short* __restrict__ hpHi,
                            short* __restrict__ hpLo, float* __restrict__ out0,
                            int* __restrict__ idx, int* __restrict__ bars) {
    int i = blockIdx.x * 256 + threadIdx.x;
    if (i < BATCH * UDIM) { h0[i] = 0.f; hpHi[i] = 0; hpLo[i] = 0; }
    if (i < BATCH * VOUTD) out0[i] = ((i & (VOUTD - 1)) == 0) ? 1.f : 0.f;
    if (i < BATCH) idx[i] = 0;
    if (i < 8) bars[i] = 0;
}

// ---------------------------------------------------------------------------
__global__ void pack_split2(const float* __restrict__ src, int rowOff, int K,
                            short* __restrict__ Hi, short* __restrict__ Lo,
                            int nChunks) {
    int gid = blockIdx.x * 256 + threadIdx.x;
    if (gid >= nChunks) return;
    int cpr = K >> 3;
    int r = gid / cpr, k0 = (gid - r * cpr) * 8;
    const float* s = src + (size_t)(rowOff + r) * K + k0;
    float v[8];
#pragma unroll
    for (int j = 0; j < 8; j++) v[j] = s[j];
    writeSplit8(Hi, Lo, pkChunk(r, k0, K), v);
}

__global__ void pack_cat(const float* __restrict__ sA, int KA, int offA,
                         const float* __restrict__ sB, int KB, int offB,
                         short* __restrict__ Hi, short* __restrict__ Lo,
                         int nChunks) {
    int gid = blockIdx.x * 256 + threadIdx.x;
    if (gid >= nChunks) return;
    int K = KA + KB;
    int cpr = K >> 3;
    int r = gid / cpr, k0 = (gid - r * cpr) * 8;
    float v[8];
    if (k0 < KA) {
        const float* s = sA + (size_t)(offA + r) * KA + k0;
#pragma unroll
        for (int j = 0; j < 8; j++) v[j] = s[j];
    } else {
        const float* s = sB + (size_t)(offB + r) * KB + (k0 - KA);
#pragma unroll
        for (int j = 0; j < 8; j++) v[j] = s[j];
    }
    writeSplit8(Hi, Lo, pkChunk(r, k0, K), v);
}

// ---------------------------------------------------------------------------
// Split-bf16 3-pass MFMA GEMM (used for enc_proj): C = A @ W^T + bias, fp32.
// ---------------------------------------------------------------------------
__global__ __launch_bounds__(256) void gemm_sp3(
    const short8* __restrict__ Ahi, const short8* __restrict__ Alo,
    const short8* __restrict__ Whi, const short8* __restrict__ Wlo,
    const float* __restrict__ bias, float* __restrict__ C,
    int KT, int N) {
    int tid = threadIdx.x, lane = tid & 63, wave = tid >> 6;
    int m16 = blockIdx.y * 4 + (wave & 1) * 2;
    int n16 = blockIdx.x * 4 + (wave >> 1) * 2;
    const short8* a0h = Ahi + (size_t)m16 * KT * 64 + lane;
    const short8* a1h = a0h + (size_t)KT * 64;
    const short8* a0l = Alo + (size_t)m16 * KT * 64 + lane;
    const short8* a1l = a0l + (size_t)KT * 64;
    const short8* w0h = Whi + (size_t)n16 * KT * 64 + lane;
    const short8* w1h = w0h + (size_t)KT * 64;
    const short8* w0l = Wlo + (size_t)n16 * KT * 64 + lane;
    const short8* w1l = w0l + (size_t)KT * 64;
    f32x4 acc00 = {0,0,0,0}, acc01 = {0,0,0,0}, acc10 = {0,0,0,0}, acc11 = {0,0,0,0};

    for (int kt = 0; kt < KT; kt++) {
        size_t o = (size_t)kt * 64;
        short8 A0H = a0h[o], A1H = a1h[o], A0L = a0l[o], A1L = a1l[o];
        short8 W0H = w0h[o], W1H = w1h[o], W0L = w0l[o], W1L = w1l[o];
        MFMA(acc00, A0H, W0H); MFMA(acc01, A0H, W1H); MFMA(acc10, A1H, W0H); MFMA(acc11, A1H, W1H);
        MFMA(acc00, A0H, W0L); MFMA(acc01, A0H, W1L); MFMA(acc10, A1H, W0L); MFMA(acc11, A1H, W1L);
        MFMA(acc00, A0L, W0H); MFMA(acc01, A0L, W1H); MFMA(acc10, A1L, W0H); MFMA(acc11, A1L, W1H);
    }
    int rsub = (lane >> 4) * 4, cn = lane & 15;
    float b0 = bias ? bias[(n16 + 0) * 16 + cn] : 0.f;
    float b1 = bias ? bias[(n16 + 1) * 16 + cn] : 0.f;
    int row0 = (m16 + 0) * 16 + rsub;
    int row1 = (m16 + 1) * 16 + rsub;
    int col0 = (n16 + 0) * 16 + cn;
    int col1 = (n16 + 1) * 16 + cn;
#pragma unroll
    for (int r = 0; r < 4; r++) {
        C[(size_t)(row0 + r) * N + col0] = acc00[r] + b0;
        C[(size_t)(row0 + r) * N + col1] = acc01[r] + b1;
        C[(size_t)(row1 + r) * N + col0] = acc10[r] + b0;
        C[(size_t)(row1 + r) * N + col1] = acc11[r] + b1;
    }
}

// ---------------------------------------------------------------------------
// Persistent encoder: 64 GRU steps in one kernel, grid barrier between steps.
// Block = (g = u-group of 16, y = batch quarter); wave owns (m16 = y*4+w, g).
// Each wave computes ALL gate planes for its tile (r,z,nh share A; balanced).
// ---------------------------------------------------------------------------
__global__ __launch_bounds__(256, 1) void enc_persistent(
    const short8* __restrict__ xHi8, const short8* __restrict__ xLo8,
    const short8* __restrict__ WrH, const short8* __restrict__ WrL,
    const short8* __restrict__ WzH, const short8* __restrict__ WzL,
    const short8* __restrict__ WnhH, const short8* __restrict__ WnhL,
    const short8* __restrict__ WniH, const short8* __restrict__ WniL,
    const float* __restrict__ bih, const float* __restrict__ bhh,
    float* __restrict__ hAF, float* __restrict__ hBF,
    short* __restrict__ hAH, short* __restrict__ hAL,
    short* __restrict__ hBH, short* __restrict__ hBL,
    short* __restrict__ eaHi, short* __restrict__ eaLo,
    const int* __restrict__ x_len, int* __restrict__ bar, int* __restrict__ gen) {
    __shared__ float sHo[4][16][16];
    __shared__ float sEo[4][16][16];
    int tid = threadIdx.x, lane = tid & 63, wave = tid >> 6;
    int g = blockIdx.x & 63, y = blockIdx.x >> 6;
    int m16 = y * 4 + wave;
    int myGen = 0;
    const short8* wrh = WrH + (size_t)g * 36 * 64 + lane;
    const short8* wrl = WrL + (size_t)g * 36 * 64 + lane;
    const short8* wzh = WzH + (size_t)g * 36 * 64 + lane;
    const short8* wzl = WzL + (size_t)g * 36 * 64 + lane;
    const short8* wnh = WnhH + (size_t)g * 32 * 64 + lane;
    const short8* wnl = WnhL + (size_t)g * 32 * 64 + lane;
    const short8* wih = WniH + (size_t)g * 4 * 64 + lane;
    const short8* wil = WniL + (size_t)g * 4 * 64 + lane;
    int cu = g * 16 + (lane & 15);
    float b_r = bih[cu] + bhh[cu];
    float b_z = bih[UDIM + cu] + bhh[UDIM + cu];
    float b_nh = bhh[2 * UDIM + cu];
    float b_ni = bih[2 * UDIM + cu];

    for (int t = 0; t < SLEN; t++) {
        if (t) gridBar(bar, gen, myGen);
        int sel = t & 1;
        const short8* hinH8 = (const short8*)(sel ? hBH : hAH);
        const short8* hinL8 = (const short8*)(sel ? hBL : hAL);
        const float* hinF = sel ? hBF : hAF;
        float* houtF = sel ? hAF : hBF;
        short* hoH = sel ? hAH : hBH;
        short* hoL = sel ? hAL : hBL;

        const short8* ah = hinH8 + (size_t)m16 * 32 * 64 + lane;
        const short8* al = hinL8 + (size_t)m16 * 32 * 64 + lane;
        const short8* xh = xHi8 + ((size_t)t * 16 + m16) * 4 * 64 + lane;
        const short8* xl = xLo8 + ((size_t)t * 16 + m16) * 4 * 64 + lane;
        f32x4 ar = {0,0,0,0}, az = {0,0,0,0}, anh = {0,0,0,0}, ani = {0,0,0,0};
        for (int kt = 0; kt < 32; kt++) {
            size_t o = (size_t)kt * 64;
            short8 AH = ah[o], AL = al[o];
            short8 RH = wrh[o], RL = wrl[o], ZH = wzh[o], ZL = wzl[o];
            short8 NH = wnh[o], NL = wnl[o];
            MFMA(ar, AH, RH); MFMA(az, AH, ZH); MFMA(anh, AH, NH);
            MFMA(ar, AH, RL); MFMA(az, AH, ZL); MFMA(anh, AH, NL);
            MFMA(ar, AL, RH); MFMA(az, AL, ZH); MFMA(anh, AL, NH);
        }
        for (int kt = 0; kt < 4; kt++) {
            size_t o = (size_t)kt * 64;
            size_t ow = (size_t)(32 + kt) * 64;
            short8 AH = xh[o], AL = xl[o];
            short8 RH = wrh[ow], RL = wrl[ow], ZH = wzh[ow], ZL = wzl[ow];
            short8 IH = wih[o], IL = wil[o];
            MFMA(ar, AH, RH); MFMA(az, AH, ZH); MFMA(ani, AH, IH);
            MFMA(ar, AH, RL); MFMA(az, AH, ZL); MFMA(ani, AH, IL);
            MFMA(ar, AL, RH); MFMA(az, AL, ZH); MFMA(ani, AL, IH);
        }
        int r0 = m16 * 16 + ((lane >> 4) << 2);
#pragma unroll
        for (int j = 0; j < 4; j++) {
            int b = r0 + j;
            float rg = sigm(ar[j] + b_r);
            float zg = sigm(az[j] + b_z);
            float nn = tanhf(ani[j] + b_ni + rg * (anh[j] + b_nh));
            float hp = hinF[(size_t)b * UDIM + cu];
            float hv = (1.f - zg) * nn + zg * hp;
            bool msk = t < x_len[b];
            float ho = msk ? hv : hp;
            houtF[(size_t)b * UDIM + cu] = ho;
            sHo[wave][((lane >> 4) << 2) + j][lane & 15] = ho;
            sEo[wave][((lane >> 4) << 2) + j][lane & 15] = msk ? hv : 0.f;
        }
        __syncthreads();
        if (lane < 32) {
            int rr = lane >> 1, oct = lane & 1;
            int brow = m16 * 16 + rr;
            int u0 = g * 16 + oct * 8;
            float v[8];
#pragma unroll
            for (int j = 0; j < 8; j++) v[j] = sHo[wave][rr][oct * 8 + j];
            writeSplit8(hoH, hoL, pkChunk(brow, u0, UDIM), v);
#pragma unroll
            for (int j = 0; j < 8; j++) v[j] = sEo[wave][rr][oct * 8 + j];
            writeSplit8(eaHi, eaLo, pkChunk(brow * SLEN + t, u0, UDIM), v);
        }
        __syncthreads();
    }
}

// ---------------------------------------------------------------------------
// Persistent decoder: 24 steps x [P2 attn | P3 GRU | P4 fc+argmax & P1 W2h].
// 3 grid barriers per step.
// ---------------------------------------------------------------------------
__global__ __launch_bounds__(256, 1) void dec_persistent(
    const short8* __restrict__ w2H, const short8* __restrict__ w2L,
    const float* __restrict__ W2_b,
    const float* __restrict__ encProj,
    const short* __restrict__ eaHi, const short* __restrict__ eaLo,
    const float* __restrict__ V_W, const float* __restrict__ V_b,
    const float* __restrict__ o2h_W, const float* __restrict__ o2h_b,
    short* __restrict__ gxHi, short* __restrict__ gxLo,
    const short8* __restrict__ WrH, const short8* __restrict__ WrL,
    const short8* __restrict__ WzH, const short8* __restrict__ WzL,
    const short8* __restrict__ WnhH, const short8* __restrict__ WnhL,
    const short8* __restrict__ WniH, const short8* __restrict__ WniL,
    const float* __restrict__ bih, const float* __restrict__ bhh,
    float* __restrict__ hAF, float* __restrict__ hBF,
    short* __restrict__ hAH, short* __restrict__ hAL,
    short* __restrict__ hBH, short* __restrict__ hBL,
    const short8* __restrict__ fcH, const short8* __restrict__ fcL,
    const float* __restrict__ fc_b,
    float* __restrict__ out, int* __restrict__ idx,
    float* __restrict__ tmp2, int* __restrict__ bar, int* __restrict__ gen) {
    __shared__ float smem[2112];
    int tid = threadIdx.x, lane = tid & 63, wave = tid >> 6;
    int g = blockIdx.x & 63, y = blockIdx.x >> 6;
    int m16 = y * 4 + wave;
    int myGen = 0;

    // ---- P1 for st=0: tmp2 = h @ W2^T + b (h = buffer A) ----
    {
        const short8* ah = (const short8*)hAH + (size_t)m16 * 32 * 64 + lane;
        const short8* al = (const short8*)hAL + (size_t)m16 * 32 * 64 + lane;
        const short8* wh = w2H + (size_t)g * 32 * 64 + lane;
        const short8* wl = w2L + (size_t)g * 32 * 64 + lane;
        f32x4 acc = {0,0,0,0};
        for (int kt = 0; kt < 32; kt++) {
            size_t o = (size_t)kt * 64;
            short8 AH = ah[o], AL = al[o], WH = wh[o], WL = wl[o];
            MFMA(acc, AH, WH); MFMA(acc, AH, WL); MFMA(acc, AL, WH);
        }
        int cu = g * 16 + (lane & 15);
        int r0 = m16 * 16 + ((lane >> 4) << 2);
        float bb = W2_b[cu];
#pragma unroll
        for (int j = 0; j < 4; j++)
            tmp2[(size_t)(r0 + j) * UDIM + cu] = acc[j] + bb;
    }

    for (int st = 0; st < TDEC - 1; st++) {
        int sel = st & 1;
        const short8* hinH8 = (const short8*)(sel ? hBH : hAH);
        const short8* hinL8 = (const short8*)(sel ? hBL : hAL);
        const float* hinF = sel ? hBF : hAF;
        float* houtF = sel ? hAF : hBF;
        short* hoH = sel ? hAH : hBH;
        short* hoL = sel ? hAL : hBL;

        gridBar(bar, gen, myGen);

        // ---- P2: attention + ctx + emb -> gx (block = batch b) ----
        {
            int b = blockIdx.x;
            float* s_t2 = smem;
            float* s_v = smem + UDIM;
            float* s_at = smem + 2 * UDIM;
            for (int u = tid; u < UDIM; u += 256) {
                s_t2[u] = tmp2[(size_t)b * UDIM + u];
                s_v[u] = V_W[u];
            }
            __syncthreads();
            for (int s = wave; s < SLEN; s += 4) {
                const float4* ep4 = (const float4*)(encProj + ((size_t)b * SLEN + s) * UDIM);
                float pp = 0.f;
                for (int u4 = lane; u4 < UDIM / 4; u4 += 64) {
                    float4 e = ep4[u4];
                    int u = 4 * u4;
                    pp += tanhf(e.x + s_t2[u]) * s_v[u] +
                          tanhf(e.y + s_t2[u + 1]) * s_v[u + 1] +
                          tanhf(e.z + s_t2[u + 2]) * s_v[u + 2] +
                          tanhf(e.w + s_t2[u + 3]) * s_v[u + 3];
                }
#pragma unroll
                for (int off = 32; off > 0; off >>= 1) pp += __shfl_xor(pp, off);
                if (lane == 0) s_at[s] = pp + V_b[0];
            }
            __syncthreads();
            if (tid < 64) {
                float v = s_at[tid];
                float mx = v;
#pragma unroll
                for (int off = 32; off > 0; off >>= 1) mx = fmaxf(mx, __shfl_xor(mx, off));
                float e = expf(v - mx);
                float sum = e;
#pragma unroll
                for (int off = 32; off > 0; off >>= 1) sum += __shfl_xor(sum, off);
                s_at[tid] = e / sum;
            }
            __syncthreads();
            if (tid < 128) {
                int u0 = tid * 8;
                float a[8] = {0,0,0,0,0,0,0,0};
                const short8* hi8 = (const short8*)eaHi;
                const short8* lo8 = (const short8*)eaLo;
                int lanePart = 16 * ((u0 >> 3) & 3);
                int colPart = u0 >> 5;
                for (int s = 0; s < SLEN; s++) {
                    int r = b * SLEN + s;
                    size_t ch = ((size_t)(r >> 4) * (UDIM >> 5) + colPart) * 64 + (r & 15) + lanePart;
                    S8 h, l;
                    h.v = hi8[ch];
                    l.v = lo8[ch];
                    float w = s_at[s];
#pragma unroll
                    for (int j = 0; j < 8; j++) a[j] += w * (bf2f(h.s[j]) + bf2f(l.s[j]));
                }
                writeSplit8(gxHi, gxLo, pkChunk(b, u0, GXW), a);
            } else if (tid < 192) {
                int e0 = (tid - 128) * 8;
                int ib = idx[b];
                float a[8];
#pragma unroll
                for (int j = 0; j < 8; j++)
                    a[j] = o2h_W[(size_t)(e0 + j) * VOUTD + ib] + o2h_b[e0 + j];
                writeSplit8(gxHi, gxLo, pkChunk(b, UDIM + e0, GXW), a);
            }
        }

        gridBar(bar, gen, myGen);

        // ---- P3: GRU step (wave owns (m16, g), all planes) ----
        {
            const short8* ah = hinH8 + (size_t)m16 * 32 * 64 + lane;
            const short8* al = hinL8 + (size_t)m16 * 32 * 64 + lane;
            const short8* gxh = (const short8*)gxHi + (size_t)m16 * 48 * 64 + lane;
            const short8* gxl = (const short8*)gxLo + (size_t)m16 * 48 * 64 + lane;
            const short8* wrh = WrH + (size_t)g * 80 * 64 + lane;
            const short8* wrl = WrL + (size_t)g * 80 * 64 + lane;
            const short8* wzh = WzH + (size_t)g * 80 * 64 + lane;
            const short8* wzl = WzL + (size_t)g * 80 * 64 + lane;
            const short8* wnh = WnhH + (size_t)g * 32 * 64 + lane;
            const short8* wnl = WnhL + (size_t)g * 32 * 64 + lane;
            const short8* wih = WniH + (size_t)g * 48 * 64 + lane;
            const short8* wil = WniL + (size_t)g * 48 * 64 + lane;
            f32x4 ar = {0,0,0,0}, az = {0,0,0,0}, anh = {0,0,0,0}, ani = {0,0,0,0};
            for (int kt = 0; kt < 32; kt++) {
                size_t o = (size_t)kt * 64;
                short8 AH = ah[o], AL = al[o];
                short8 RH = wrh[o], RL = wrl[o], ZH = wzh[o], ZL = wzl[o];
                short8 NH = wnh[o], NL = wnl[o];
                MFMA(ar, AH, RH); MFMA(az, AH, ZH); MFMA(anh, AH, NH);
                MFMA(ar, AH, RL); MFMA(az, AH, ZL); MFMA(anh, AH, NL);
                MFMA(ar, AL, RH); MFMA(az, AL, ZH); MFMA(anh, AL, NH);
            }
            for (int kt = 0; kt < 48; kt++) {
                size_t o = (size_t)kt * 64;
                size_t ow = (size_t)(32 + kt) * 64;
                short8 AH = gxh[o], AL = gxl[o];
                short8 RH = wrh[ow], RL = wrl[ow], ZH = wzh[ow], ZL = wzl[ow];
                short8 IH = wih[o], IL = wil[o];
                MFMA(ar, AH, RH); MFMA(az, AH, ZH); MFMA(ani, AH, IH);
                MFMA(ar, AH, RL); MFMA(az, AH, ZL); MFMA(ani, AH, IL);
                MFMA(ar, AL, RH); MFMA(az, AL, ZH); MFMA(ani, AL, IH);
            }
            int cu = g * 16 + (lane & 15);
            int r0 = m16 * 16 + ((lane >> 4) << 2);
            float b_r = bih[cu] + bhh[cu];
            float b_z = bih[UDIM + cu] + bhh[UDIM + cu];
            float b_nh = bhh[2 * UDIM + cu];
            float b_ni = bih[2 * UDIM + cu];
            float (*sHo)[16][16] = (float(*)[16][16])smem;
#pragma unroll
            for (int j = 0; j < 4; j++) {
                int b = r0 + j;
                float rg = sigm(ar[j] + b_r);
                float zg = sigm(az[j] + b_z);
                float nn = tanhf(ani[j] + b_ni + rg * (anh[j] + b_nh));
                float hp = hinF[(size_t)b * UDIM + cu];
                float hv = (1.f - zg) * nn + zg * hp;
                houtF[(size_t)b * UDIM + cu] = hv;
                sHo[wave][((lane >> 4) << 2) + j][lane & 15] = hv;
            }
            __syncthreads();
            if (lane < 32) {
                int rr = lane >> 1, oct = lane & 1;
                int brow = m16 * 16 + rr;
                int u0 = g * 16 + oct * 8;
                float v[8];
#pragma unroll
                for (int j = 0; j < 8; j++) v[j] = sHo[wave][rr][oct * 8 + j];
                writeSplit8(hoH, hoL, pkChunk(brow, u0, UDIM), v);
            }
        }

        gridBar(bar, gen, myGen);

        // ---- P4: pred = h_new @ fc^T + b, first-max argmax (blocks 0..15) ----
        if (blockIdx.x < 16) {
            int fm = blockIdx.x;
            const short8* ah = (const short8*)hoH + (size_t)fm * 32 * 64 + lane;
            const short8* al = (const short8*)hoL + (size_t)fm * 32 * 64 + lane;
            int n0 = 2 * wave, n1 = 2 * wave + 1;
            const short8* w0h = fcH + (size_t)n0 * 32 * 64 + lane;
            const short8* w0l = fcL + (size_t)n0 * 32 * 64 + lane;
            const short8* w1h = fcH + (size_t)n1 * 32 * 64 + lane;
            const short8* w1l = fcL + (size_t)n1 * 32 * 64 + lane;
            f32x4 a0 = {0,0,0,0}, a1 = {0,0,0,0};
            for (int kt = 0; kt < 32; kt++) {
                size_t o = (size_t)kt * 64;
                short8 AH = ah[o], AL = al[o];
                short8 W0H = w0h[o], W0L = w0l[o], W1H = w1h[o], W1L = w1l[o];
                MFMA(a0, AH, W0H); MFMA(a1, AH, W1H);
                MFMA(a0, AH, W0L); MFMA(a1, AH, W1L);
                MFMA(a0, AL, W0H); MFMA(a1, AL, W1H);
            }
            float (*sP)[129] = (float(*)[129])smem;
            int cn = lane & 15, rsub = (lane >> 4) << 2;
#pragma unroll
            for (int j = 0; j < 4; j++) {
                sP[rsub + j][n0 * 16 + cn] = a0[j] + fc_b[n0 * 16 + cn];
                sP[rsub + j][n1 * 16 + cn] = a1[j] + fc_b[n1 * 16 + cn];
            }
            __syncthreads();
            float* pred = out + (size_t)(1 + st) * BATCH * VOUTD + (size_t)fm * 16 * VOUTD;
            {
                int row = tid >> 4, c0 = (tid & 15) * 8;
#pragma unroll
                for (int j = 0; j < 8; j++)
                    pred[(size_t)row * VOUTD + c0 + j] = sP[row][c0 + j];
            }
            if (tid < 16) {
                float v = sP[tid][0];
                int bi = 0;
                for (int j = 1; j < VOUTD; j++) {
                    float w = sP[tid][j];
                    if (w > v) { v = w; bi = j; }
                }
                idx[fm * 16 + tid] = bi;
            }
        }

        // ---- P1 for st+1: tmp2 = h_new @ W2^T + b ----
        if (st < TDEC - 2) {
            const short8* ah = (const short8*)hoH + (size_t)m16 * 32 * 64 + lane;
            const short8* al = (const short8*)hoL + (size_t)m16 * 32 * 64 + lane;
            const short8* wh = w2H + (size_t)g * 32 * 64 + lane;
            const short8* wl = w2L + (size_t)g * 32 * 64 + lane;
            f32x4 acc = {0,0,0,0};
            for (int kt = 0; kt < 32; kt++) {
                size_t o = (size_t)kt * 64;
                short8 AH = ah[o], AL = al[o], WH = wh[o], WL = wl[o];
                MFMA(acc, AH, WH); MFMA(acc, AH, WL); MFMA(acc, AL, WH);
            }
            int cu = g * 16 + (lane & 15);
            int r0 = m16 * 16 + ((lane >> 4) << 2);
            float bb = W2_b[cu];
#pragma unroll
            for (int j = 0; j < 4; j++)
                tmp2[(size_t)(r0 + j) * UDIM + cu] = acc[j] + bb;
        }
    }
}

// ---------------------------------------------------------------------------
extern "C" void kernel_launch(void* const* d_in, const int* in_sizes, int n_in,
                              void* d_out, int out_size, void* d_ws, size_t ws_size,
                              hipStream_t stream) {
    const float* x       = (const float*)d_in[0];
    const int*   x_len   = (const int*)d_in[1];
    const float* enc_Wih = (const float*)d_in[2];
    const float* enc_Whh = (const float*)d_in[3];
    const float* enc_bih = (const float*)d_in[4];
    const float* enc_bhh = (const float*)d_in[5];
    const float* dec_Wih = (const float*)d_in[6];
    const float* dec_Whh = (const float*)d_in[7];
    const float* dec_bih = (const float*)d_in[8];
    const float* dec_bhh = (const float*)d_in[9];
    const float* o2h_W   = (const float*)d_in[10];
    const float* o2h_b   = (const float*)d_in[11];
    const float* fc_W    = (const float*)d_in[12];
    const float* fc_b    = (const float*)d_in[13];
    const float* W1_W    = (const float*)d_in[14];
    const float* W1_b    = (const float*)d_in[15];
    const float* W2_W    = (const float*)d_in[16];
    const float* W2_b    = (const float*)d_in[17];
    const float* V_W     = (const float*)d_in[18];
    const float* V_b     = (const float*)d_in[19];
    float* out = (float*)d_out;

    char* p = (char*)d_ws;
    auto alloc = [&](size_t bytes) -> char* {
        char* q = p;
        p += (bytes + 255) & ~(size_t)255;
        return q;
    };
    float* hAF  = (float*)alloc((size_t)BATCH * UDIM * 4);
    float* hBF  = (float*)alloc((size_t)BATCH * UDIM * 4);
    short* hAH  = (short*)alloc((size_t)BATCH * UDIM * 2);
    short* hAL  = (short*)alloc((size_t)BATCH * UDIM * 2);
    short* hBH  = (short*)alloc((size_t)BATCH * UDIM * 2);
    short* hBL  = (short*)alloc((size_t)BATCH * UDIM * 2);
    float* tmp2 = (float*)alloc((size_t)BATCH * UDIM * 4);
    short* gxHi = (short*)alloc((size_t)BATCH * GXW * 2);
    short* gxLo = (short*)alloc((size_t)BATCH * GXW * 2);
    short* encAHi = (short*)alloc((size_t)BATCH * SLEN * UDIM * 2);
    short* encALo = (short*)alloc((size_t)BATCH * SLEN * UDIM * 2);
    float* encProjF = (float*)alloc((size_t)BATCH * SLEN * UDIM * 4);
    short* eWrH = (short*)alloc((size_t)UDIM * 1152 * 2);
    short* eWrL = (short*)alloc((size_t)UDIM * 1152 * 2);
    short* eWzH = (short*)alloc((size_t)UDIM * 1152 * 2);
    short* eWzL = (short*)alloc((size_t)UDIM * 1152 * 2);
    short* eWnhH = (short*)alloc((size_t)UDIM * UDIM * 2);
    short* eWnhL = (short*)alloc((size_t)UDIM * UDIM * 2);
    short* eWniH = (short*)alloc((size_t)UDIM * VIND * 2);
    short* eWniL = (short*)alloc((size_t)UDIM * VIND * 2);
    short* dWrH = (short*)alloc((size_t)UDIM * 2560 * 2);
    short* dWrL = (short*)alloc((size_t)UDIM * 2560 * 2);
    short* dWzH = (short*)alloc((size_t)UDIM * 2560 * 2);
    short* dWzL = (short*)alloc((size_t)UDIM * 2560 * 2);
    short* dWnhH = (short*)alloc((size_t)UDIM * UDIM * 2);
    short* dWnhL = (short*)alloc((size_t)UDIM * UDIM * 2);
    short* dWniH = (short*)alloc((size_t)UDIM * GXW * 2);
    short* dWniL = (short*)alloc((size_t)UDIM * GXW * 2);
    short* w1Hi = (short*)alloc((size_t)UDIM * UDIM * 2);
    short* w1Lo = (short*)alloc((size_t)UDIM * UDIM * 2);
    short* w2Hi = (short*)alloc((size_t)UDIM * UDIM * 2);
    short* w2Lo = (short*)alloc((size_t)UDIM * UDIM * 2);
    short* fcHi = (short*)alloc((size_t)VOUTD * UDIM * 2);
    short* fcLo = (short*)alloc((size_t)VOUTD * UDIM * 2);
    short* xHi  = (short*)alloc((size_t)SLEN * BATCH * VIND * 2);
    short* xLo  = (short*)alloc((size_t)SLEN * BATCH * VIND * 2);
    int*   idx  = (int*)alloc(BATCH * 4);
    int*   bars = (int*)alloc(8 * 4);

    init_kernel<<<(BATCH * UDIM + 255) / 256, 256, 0, stream>>>(hAF, hAH, hAL, out, idx, bars);

    auto packP = [&](const float* src, int rowOff, int K, short* Hi, short* Lo, int R) {
        int chunks = R * K / 8;
        pack_split2<<<(chunks + 255) / 256, 256, 0, stream>>>(src, rowOff, K, Hi, Lo, chunks);
    };
    auto packC = [&](const float* sA, int KA, int offA, const float* sB, int KB, int offB,
                     short* Hi, short* Lo, int R) {
        int chunks = R * (KA + KB) / 8;
        pack_cat<<<(chunks + 255) / 256, 256, 0, stream>>>(sA, KA, offA, sB, KB, offB, Hi, Lo, chunks);
    };
    packC(enc_Whh, UDIM, 0,        enc_Wih, VIND, 0,        eWrH, eWrL, UDIM);
    packC(enc_Whh, UDIM, UDIM,     enc_Wih, VIND, UDIM,     eWzH, eWzL, UDIM);
    packP(enc_Whh, 2 * UDIM, UDIM, eWnhH, eWnhL, UDIM);
    packP(enc_Wih, 2 * UDIM, VIND, eWniH, eWniL, UDIM);
    packC(dec_Whh, UDIM, 0,        dec_Wih, GXW, 0,         dWrH, dWrL, UDIM);
    packC(dec_Whh, UDIM, UDIM,     dec_Wih, GXW, UDIM,      dWzH, dWzL, UDIM);
    packP(dec_Whh, 2 * UDIM, UDIM, dWnhH, dWnhL, UDIM);
    packP(dec_Wih, 2 * UDIM, GXW,  dWniH, dWniL, UDIM);
    packP(W1_W, 0, UDIM, w1Hi, w1Lo, UDIM);
    packP(W2_W, 0, UDIM, w2Hi, w2Lo, UDIM);
    packP(fc_W, 0, UDIM, fcHi, fcLo, VOUTD);
    packP(x, 0, VIND, xHi, xLo, SLEN * BATCH);

    // ---- encoder: all 64 steps in one persistent kernel ----
    enc_persistent<<<NBLK, 256, 0, stream>>>(
        (const short8*)xHi, (const short8*)xLo,
        (const short8*)eWrH, (const short8*)eWrL,
        (const short8*)eWzH, (const short8*)eWzL,
        (const short8*)eWnhH, (const short8*)eWnhL,
        (const short8*)eWniH, (const short8*)eWniL,
        enc_bih, enc_bhh, hAF, hBF, hAH, hAL, hBH, hBL,
        encAHi, encALo, x_len, bars + 0, bars + 1);

    // ---- enc_proj = enc_out @ W1^T + W1_b (fp32, precision-critical) ----
    gemm_sp3<<<dim3(UDIM / 64, SLEN * BATCH / 64), 256, 0, stream>>>(
        (const short8*)encAHi, (const short8*)encALo,
        (const short8*)w1Hi, (const short8*)w1Lo,
        W1_b, encProjF, UDIM / 32, UDIM);

    // ---- decoder: all 24 steps in one persistent kernel ----
    dec_persistent<<<NBLK, 256, 0, stream>>>(
        (const short8*)w2Hi, (const short8*)w2Lo, W2_b,
        encProjF, encAHi, encALo, V_W, V_b, o2h_W, o2h_b,
        gxHi, gxLo,
        (const short8*)dWrH, (const short8*)dWrL,
        (const short8*)dWzH, (const short8*)dWzL,
        (const short8*)dWnhH, (const short8*)dWnhL,
        (const short8*)dWniH, (const short8*)dWniL,
        dec_bih, dec_bhh, hAF, hBF, hAH, hAL, hBH, hBL,
        (const short8*)fcHi, (const short8*)fcLo, fc_b,
        out, idx, tmp2, bars + 2, bars + 3);
}

// Round 8
// 5669.628 us; speedup vs baseline: 2.2100x; 2.2100x over previous
//
#include <hip/hip_runtime.h>
#include <math.h>

#define SLEN 64
#define BATCH 256
#define VIND 128
#define VOUTD 128
#define UDIM 1024
#define EDIM 512
#define TDEC 25
#define GXW 1536
#define U3 3072

typedef __attribute__((ext_vector_type(8))) short short8;
typedef __attribute__((ext_vector_type(4))) float f32x4;

#define MFMA(acc, A, B) acc = __builtin_amdgcn_mfma_f32_16x16x32_bf16((A), (B), (acc), 0, 0, 0)

__device__ __forceinline__ float sigm(float x) { return 1.f / (1.f + expf(-x)); }

__device__ __forceinline__ short f2bf(float f) {
    unsigned u = __float_as_uint(f);
    u += 0x7FFF + ((u >> 16) & 1);
    return (short)(u >> 16);
}
__device__ __forceinline__ float bf2f(short h) {
    return __uint_as_float(((unsigned)(unsigned short)h) << 16);
}

// fragment-major packed layout for operand X[R][K]:
// chunk(r,k) holds X[r][k..k+8); lane = (r&15) + 16*((k>>3)&3)
__device__ __forceinline__ size_t pkChunk(int r, int k, int K) {
    return ((size_t)(r >> 4) * (K >> 5) + (k >> 5)) * 64 + ((r & 15) + 16 * ((k >> 3) & 3));
}

union S8 { short s[8]; short8 v; };

__device__ __forceinline__ void writeSplit8(short* Hi, short* Lo, size_t chunk,
                                            const float* vals) {
    S8 h, l;
#pragma unroll
    for (int j = 0; j < 8; j++) {
        short hb = f2bf(vals[j]);
        h.s[j] = hb;
        l.s[j] = f2bf(vals[j] - bf2f(hb));
    }
    ((short8*)Hi)[chunk] = h.v;
    ((short8*)Lo)[chunk] = l.v;
}

// ---------------------------------------------------------------------------
__global__ void init_kernel(float* __restrict__ h0, short* __restrict__ hpHi,
                            short* __restrict__ hpLo, float* __restrict__ out0,
                            int* __restrict__ idx) {
    int i = blockIdx.x * 256 + threadIdx.x;
    if (i < BATCH * UDIM) { h0[i] = 0.f; hpHi[i] = 0; hpLo[i] = 0; }
    if (i < BATCH * VOUTD) out0[i] = ((i & (VOUTD - 1)) == 0) ? 1.f : 0.f;
    if (i < BATCH) idx[i] = 0;
}

// ---------------------------------------------------------------------------
__global__ void pack_split2(const float* __restrict__ src, int rowOff, int K,
                            short* __restrict__ Hi, short* __restrict__ Lo,
                            int nChunks) {
    int gid = blockIdx.x * 256 + threadIdx.x;
    if (gid >= nChunks) return;
    int cpr = K >> 3;
    int r = gid / cpr, k0 = (gid - r * cpr) * 8;
    const float* s = src + (size_t)(rowOff + r) * K + k0;
    float v[8];
#pragma unroll
    for (int j = 0; j < 8; j++) v[j] = s[j];
    writeSplit8(Hi, Lo, pkChunk(r, k0, K), v);
}

__global__ void pack_cat(const float* __restrict__ sA, int KA, int offA,
                         const float* __restrict__ sB, int KB, int offB,
                         short* __restrict__ Hi, short* __restrict__ Lo,
                         int nChunks) {
    int gid = blockIdx.x * 256 + threadIdx.x;
    if (gid >= nChunks) return;
    int K = KA + KB;
    int cpr = K >> 3;
    int r = gid / cpr, k0 = (gid - r * cpr) * 8;
    float v[8];
    if (k0 < KA) {
        const float* s = sA + (size_t)(offA + r) * KA + k0;
#pragma unroll
        for (int j = 0; j < 8; j++) v[j] = s[j];
    } else {
        const float* s = sB + (size_t)(offB + r) * KB + (k0 - KA);
#pragma unroll
        for (int j = 0; j < 8; j++) v[j] = s[j];
    }
    writeSplit8(Hi, Lo, pkChunk(r, k0, K), v);
}

// ---------------------------------------------------------------------------
// Split-bf16 3-pass MFMA GEMM: C = A @ W^T + bias, fp32 out.
// Grid (M/64, N/64): m from blockIdx.x — with gridDim.x % 8 == 0 all blocks
// sharing an A-tile land on one XCD (L2 locality).
// ---------------------------------------------------------------------------
__global__ __launch_bounds__(256) void gemm_sp3(
    const short8* __restrict__ Ahi, const short8* __restrict__ Alo,
    const short8* __restrict__ Whi, const short8* __restrict__ Wlo,
    const float* __restrict__ bias, float* __restrict__ C,
    int KT, int N) {
    int tid = threadIdx.x, lane = tid & 63, wave = tid >> 6;
    int m16 = blockIdx.x * 4 + (wave & 1) * 2;
    int n16 = blockIdx.y * 4 + (wave >> 1) * 2;
    const short8* a0h = Ahi + (size_t)m16 * KT * 64 + lane;
    const short8* a1h = a0h + (size_t)KT * 64;
    const short8* a0l = Alo + (size_t)m16 * KT * 64 + lane;
    const short8* a1l = a0l + (size_t)KT * 64;
    const short8* w0h = Whi + (size_t)n16 * KT * 64 + lane;
    const short8* w1h = w0h + (size_t)KT * 64;
    const short8* w0l = Wlo + (size_t)n16 * KT * 64 + lane;
    const short8* w1l = w0l + (size_t)KT * 64;
    f32x4 acc00 = {0,0,0,0}, acc01 = {0,0,0,0}, acc10 = {0,0,0,0}, acc11 = {0,0,0,0};

    for (int kt = 0; kt < KT; kt++) {
        size_t o = (size_t)kt * 64;
        short8 A0H = a0h[o], A1H = a1h[o], A0L = a0l[o], A1L = a1l[o];
        short8 W0H = w0h[o], W1H = w1h[o], W0L = w0l[o], W1L = w1l[o];
        MFMA(acc00, A0H, W0H); MFMA(acc01, A0H, W1H); MFMA(acc10, A1H, W0H); MFMA(acc11, A1H, W1H);
        MFMA(acc00, A0H, W0L); MFMA(acc01, A0H, W1L); MFMA(acc10, A1H, W0L); MFMA(acc11, A1H, W1L);
        MFMA(acc00, A0L, W0H); MFMA(acc01, A0L, W1H); MFMA(acc10, A1L, W0H); MFMA(acc11, A1L, W1H);
    }
    int rsub = (lane >> 4) * 4, cn = lane & 15;
    float b0 = bias ? bias[(n16 + 0) * 16 + cn] : 0.f;
    float b1 = bias ? bias[(n16 + 1) * 16 + cn] : 0.f;
    int row0 = (m16 + 0) * 16 + rsub;
    int row1 = (m16 + 1) * 16 + rsub;
    int col0 = (n16 + 0) * 16 + cn;
    int col1 = (n16 + 1) * 16 + cn;
#pragma unroll
    for (int r = 0; r < 4; r++) {
        C[(size_t)(row0 + r) * N + col0] = acc00[r] + b0;
        C[(size_t)(row0 + r) * N + col1] = acc01[r] + b1;
        C[(size_t)(row1 + r) * N + col0] = acc10[r] + b0;
        C[(size_t)(row1 + r) * N + col1] = acc11[r] + b1;
    }
}

// ---------------------------------------------------------------------------
// BM=32 variant for skinny-M GEMMs (W2). Grid (M/32, N/64).
// ---------------------------------------------------------------------------
__global__ __launch_bounds__(256) void gemm_bm32(
    const short8* __restrict__ Ahi, const short8* __restrict__ Alo,
    const short8* __restrict__ Whi, const short8* __restrict__ Wlo,
    const float* __restrict__ bias, float* __restrict__ C,
    int KT, int N) {
    int tid = threadIdx.x, lane = tid & 63, wave = tid >> 6;
    int m16 = blockIdx.x * 2 + (wave & 1);
    int n16 = blockIdx.y * 4 + (wave >> 1) * 2;
    const short8* ah = Ahi + (size_t)m16 * KT * 64 + lane;
    const short8* al = Alo + (size_t)m16 * KT * 64 + lane;
    const short8* w0h = Whi + (size_t)n16 * KT * 64 + lane;
    const short8* w1h = w0h + (size_t)KT * 64;
    const short8* w0l = Wlo + (size_t)n16 * KT * 64 + lane;
    const short8* w1l = w0l + (size_t)KT * 64;
    f32x4 a0 = {0,0,0,0}, a1 = {0,0,0,0};
    for (int kt = 0; kt < KT; kt++) {
        size_t o = (size_t)kt * 64;
        short8 AH = ah[o], AL = al[o];
        short8 W0H = w0h[o], W0L = w0l[o], W1H = w1h[o], W1L = w1l[o];
        MFMA(a0, AH, W0H); MFMA(a1, AH, W1H);
        MFMA(a0, AH, W0L); MFMA(a1, AH, W1L);
        MFMA(a0, AL, W0H); MFMA(a1, AL, W1H);
    }
    int rsub = (lane >> 4) * 4, cn = lane & 15;
    float b0 = bias ? bias[(n16 + 0) * 16 + cn] : 0.f;
    float b1 = bias ? bias[(n16 + 1) * 16 + cn] : 0.f;
#pragma unroll
    for (int r = 0; r < 4; r++) {
        int row = m16 * 16 + rsub + r;
        C[(size_t)row * N + (n16 + 0) * 16 + cn] = a0[r] + b0;
        C[(size_t)row * N + (n16 + 1) * 16 + cn] = a1[r] + b1;
    }
}

// ---------------------------------------------------------------------------
// Encoder fused GRU step: K=1024 over h; gi (precomputed ih-gates) read in
// epilogue. Grid (64 g, 4 y): g%8 stable XCD -> weights L2-resident.
// Wave owns (m16 = y*4+wave, g): computes r,z,nh planes.
// ---------------------------------------------------------------------------
__global__ __launch_bounds__(256) void enc_gru(
    const short8* __restrict__ hinH8, const short8* __restrict__ hinL8,
    const short8* __restrict__ WrH, const short8* __restrict__ WrL,
    const short8* __restrict__ WzH, const short8* __restrict__ WzL,
    const short8* __restrict__ WnH, const short8* __restrict__ WnL,
    const float* __restrict__ gi,   // [2048, 3072] chunk; row = (t&7)*256 + b
    const float* __restrict__ bih, const float* __restrict__ bhh,
    const float* __restrict__ hinF, float* __restrict__ houtF,
    short* __restrict__ hoH, short* __restrict__ hoL,
    short* __restrict__ eaHi, short* __restrict__ eaLo,
    const int* __restrict__ x_len, int t) {
    __shared__ float sHo[4][16][16];
    __shared__ float sEo[4][16][16];
    int tid = threadIdx.x, lane = tid & 63, wave = tid >> 6;
    int g = blockIdx.x;
    int m16 = blockIdx.y * 4 + wave;
    const short8* ah = hinH8 + (size_t)m16 * 32 * 64 + lane;
    const short8* al = hinL8 + (size_t)m16 * 32 * 64 + lane;
    const short8* wrh = WrH + (size_t)g * 32 * 64 + lane;
    const short8* wrl = WrL + (size_t)g * 32 * 64 + lane;
    const short8* wzh = WzH + (size_t)g * 32 * 64 + lane;
    const short8* wzl = WzL + (size_t)g * 32 * 64 + lane;
    const short8* wnh = WnH + (size_t)g * 32 * 64 + lane;
    const short8* wnl = WnL + (size_t)g * 32 * 64 + lane;
    f32x4 ar = {0,0,0,0}, az = {0,0,0,0}, anh = {0,0,0,0};
    for (int kt = 0; kt < 32; kt++) {
        size_t o = (size_t)kt * 64;
        short8 AH = ah[o], AL = al[o];
        short8 RH = wrh[o], RL = wrl[o], ZH = wzh[o], ZL = wzl[o];
        short8 NH = wnh[o], NL = wnl[o];
        MFMA(ar, AH, RH); MFMA(az, AH, ZH); MFMA(anh, AH, NH);
        MFMA(ar, AH, RL); MFMA(az, AH, ZL); MFMA(anh, AH, NL);
        MFMA(ar, AL, RH); MFMA(az, AL, ZH); MFMA(anh, AL, NH);
    }
    int cu = g * 16 + (lane & 15);
    int rsub = (lane >> 4) << 2;
    int r0 = m16 * 16 + rsub;
    float b_r = bih[cu] + bhh[cu];
    float b_z = bih[UDIM + cu] + bhh[UDIM + cu];
    float b_nh = bhh[2 * UDIM + cu];
    float b_ni = bih[2 * UDIM + cu];
    int growLocal = (t & 7) * 256;
#pragma unroll
    for (int j = 0; j < 4; j++) {
        int b = r0 + j;
        const float* gr = gi + (size_t)(growLocal + b) * U3;
        float rg = sigm(ar[j] + gr[cu] + b_r);
        float zg = sigm(az[j] + gr[UDIM + cu] + b_z);
        float nn = tanhf(gr[2 * UDIM + cu] + b_ni + rg * (anh[j] + b_nh));
        float hp = hinF[(size_t)b * UDIM + cu];
        float hv = (1.f - zg) * nn + zg * hp;
        bool msk = t < x_len[b];
        float ho = msk ? hv : hp;
        houtF[(size_t)b * UDIM + cu] = ho;
        sHo[wave][rsub + j][lane & 15] = ho;
        sEo[wave][rsub + j][lane & 15] = msk ? hv : 0.f;
    }
    __syncthreads();
    if (lane < 32) {
        int rr = lane >> 1, oct = lane & 1;
        int brow = m16 * 16 + rr;
        int u0 = g * 16 + oct * 8;
        float v[8];
#pragma unroll
        for (int j = 0; j < 8; j++) v[j] = sHo[wave][rr][oct * 8 + j];
        writeSplit8(hoH, hoL, pkChunk(brow, u0, UDIM), v);
#pragma unroll
        for (int j = 0; j < 8; j++) v[j] = sEo[wave][rr][oct * 8 + j];
        writeSplit8(eaHi, eaLo, pkChunk(brow * SLEN + t, u0, UDIM), v);
    }
}

// ---------------------------------------------------------------------------
// Decoder fused GRU step: A = [h (32 kt) | gx (48 kt)]; r,z over full K,
// nh over h-part, ni over gx-part. Grid (64, 4).
// ---------------------------------------------------------------------------
__global__ __launch_bounds__(256) void dec_gru(
    const short8* __restrict__ hinH8, const short8* __restrict__ hinL8,
    const short8* __restrict__ gxH8, const short8* __restrict__ gxL8,
    const short8* __restrict__ WrH, const short8* __restrict__ WrL,
    const short8* __restrict__ WzH, const short8* __restrict__ WzL,
    const short8* __restrict__ WnhH, const short8* __restrict__ WnhL,
    const short8* __restrict__ WniH, const short8* __restrict__ WniL,
    const float* __restrict__ bih, const float* __restrict__ bhh,
    const float* __restrict__ hinF, float* __restrict__ houtF,
    short* __restrict__ hoH, short* __restrict__ hoL) {
    __shared__ float sHo[4][16][16];
    int tid = threadIdx.x, lane = tid & 63, wave = tid >> 6;
    int g = blockIdx.x;
    int m16 = blockIdx.y * 4 + wave;
    const short8* ah = hinH8 + (size_t)m16 * 32 * 64 + lane;
    const short8* al = hinL8 + (size_t)m16 * 32 * 64 + lane;
    const short8* gxh = gxH8 + (size_t)m16 * 48 * 64 + lane;
    const short8* gxl = gxL8 + (size_t)m16 * 48 * 64 + lane;
    const short8* wrh = WrH + (size_t)g * 80 * 64 + lane;
    const short8* wrl = WrL + (size_t)g * 80 * 64 + lane;
    const short8* wzh = WzH + (size_t)g * 80 * 64 + lane;
    const short8* wzl = WzL + (size_t)g * 80 * 64 + lane;
    const short8* wnh = WnhH + (size_t)g * 32 * 64 + lane;
    const short8* wnl = WnhL + (size_t)g * 32 * 64 + lane;
    const short8* wih = WniH + (size_t)g * 48 * 64 + lane;
    const short8* wil = WniL + (size_t)g * 48 * 64 + lane;
    f32x4 ar = {0,0,0,0}, az = {0,0,0,0}, anh = {0,0,0,0}, ani = {0,0,0,0};
    for (int kt = 0; kt < 32; kt++) {
        size_t o = (size_t)kt * 64;
        short8 AH = ah[o], AL = al[o];
        short8 RH = wrh[o], RL = wrl[o], ZH = wzh[o], ZL = wzl[o];
        short8 NH = wnh[o], NL = wnl[o];
        MFMA(ar, AH, RH); MFMA(az, AH, ZH); MFMA(anh, AH, NH);
        MFMA(ar, AH, RL); MFMA(az, AH, ZL); MFMA(anh, AH, NL);
        MFMA(ar, AL, RH); MFMA(az, AL, ZH); MFMA(anh, AL, NH);
    }
    for (int kt = 0; kt < 48; kt++) {
        size_t o = (size_t)kt * 64;
        size_t ow = (size_t)(32 + kt) * 64;
        short8 AH = gxh[o], AL = gxl[o];
        short8 RH = wrh[ow], RL = wrl[ow], ZH = wzh[ow], ZL = wzl[ow];
        short8 IH = wih[o], IL = wil[o];
        MFMA(ar, AH, RH); MFMA(az, AH, ZH); MFMA(ani, AH, IH);
        MFMA(ar, AH, RL); MFMA(az, AH, ZL); MFMA(ani, AH, IL);
        MFMA(ar, AL, RH); MFMA(az, AL, ZH); MFMA(ani, AL, IH);
    }
    int cu = g * 16 + (lane & 15);
    int rsub = (lane >> 4) << 2;
    int r0 = m16 * 16 + rsub;
    float b_r = bih[cu] + bhh[cu];
    float b_z = bih[UDIM + cu] + bhh[UDIM + cu];
    float b_nh = bhh[2 * UDIM + cu];
    float b_ni = bih[2 * UDIM + cu];
#pragma unroll
    for (int j = 0; j < 4; j++) {
        int b = r0 + j;
        float rg = sigm(ar[j] + b_r);
        float zg = sigm(az[j] + b_z);
        float nn = tanhf(ani[j] + b_ni + rg * (anh[j] + b_nh));
        float hp = hinF[(size_t)b * UDIM + cu];
        float hv = (1.f - zg) * nn + zg * hp;
        houtF[(size_t)b * UDIM + cu] = hv;
        sHo[wave][rsub + j][lane & 15] = hv;
    }
    __syncthreads();
    if (lane < 32) {
        int rr = lane >> 1, oct = lane & 1;
        int brow = m16 * 16 + rr;
        int u0 = g * 16 + oct * 8;
        float v[8];
#pragma unroll
        for (int j = 0; j < 8; j++) v[j] = sHo[wave][rr][oct * 8 + j];
        writeSplit8(hoH, hoL, pkChunk(brow, u0, UDIM), v);
    }
}

// ---------------------------------------------------------------------------
// Attention scores + softmax + context + emb gather -> gx split-pack [B,1536]
// ---------------------------------------------------------------------------
__global__ __launch_bounds__(256) void attn_ctx(
    const float* __restrict__ encProj,
    const short* __restrict__ eaHi, const short* __restrict__ eaLo,
    const float* __restrict__ tmp2, const float* __restrict__ V_W,
    const float* __restrict__ V_b,
    const float* __restrict__ o2h_W, const float* __restrict__ o2h_b,
    const int* __restrict__ idx, short* __restrict__ gxHi, short* __restrict__ gxLo) {
    int b = blockIdx.x;
    int tid = threadIdx.x, lane = tid & 63, wave = tid >> 6;
    __shared__ float s_t2[UDIM];
    __shared__ float s_v[UDIM];
    __shared__ float s_attn[SLEN];
    for (int u = tid; u < UDIM; u += 256) {
        s_t2[u] = tmp2[(size_t)b * UDIM + u];
        s_v[u] = V_W[u];
    }
    __syncthreads();
    for (int s = wave; s < SLEN; s += 4) {
        const float4* ep4 = (const float4*)(encProj + ((size_t)b * SLEN + s) * UDIM);
        float p = 0.f;
        for (int u4 = lane; u4 < UDIM / 4; u4 += 64) {
            float4 e = ep4[u4];
            int u = 4 * u4;
            p += tanhf(e.x + s_t2[u]) * s_v[u] +
                 tanhf(e.y + s_t2[u + 1]) * s_v[u + 1] +
                 tanhf(e.z + s_t2[u + 2]) * s_v[u + 2] +
                 tanhf(e.w + s_t2[u + 3]) * s_v[u + 3];
        }
#pragma unroll
        for (int off = 32; off > 0; off >>= 1) p += __shfl_xor(p, off);
        if (lane == 0) s_attn[s] = p + V_b[0];
    }
    __syncthreads();
    if (tid < 64) {
        float v = s_attn[tid];
        float mx = v;
#pragma unroll
        for (int off = 32; off > 0; off >>= 1) mx = fmaxf(mx, __shfl_xor(mx, off));
        float e = expf(v - mx);
        float sum = e;
#pragma unroll
        for (int off = 32; off > 0; off >>= 1) sum += __shfl_xor(sum, off);
        s_attn[tid] = e / sum;
    }
    __syncthreads();
    if (tid < 128) {
        int u0 = tid * 8;
        float a[8] = {0, 0, 0, 0, 0, 0, 0, 0};
        const short8* hi8 = (const short8*)eaHi;
        const short8* lo8 = (const short8*)eaLo;
        int lanePart = 16 * ((u0 >> 3) & 3);
        int colPart = u0 >> 5;
        for (int s = 0; s < SLEN; s++) {
            int r = b * SLEN + s;
            size_t ch = ((size_t)(r >> 4) * (UDIM >> 5) + colPart) * 64 + (r & 15) + lanePart;
            S8 h, l;
            h.v = hi8[ch];
            l.v = lo8[ch];
            float w = s_attn[s];
#pragma unroll
            for (int j = 0; j < 8; j++) a[j] += w * (bf2f(h.s[j]) + bf2f(l.s[j]));
        }
        writeSplit8(gxHi, gxLo, pkChunk(b, u0, GXW), a);
    } else if (tid < 192) {
        int e0 = (tid - 128) * 8;
        int ib = idx[b];
        float a[8];
#pragma unroll
        for (int j = 0; j < 8; j++)
            a[j] = o2h_W[(size_t)(e0 + j) * VOUTD + ib] + o2h_b[e0 + j];
        writeSplit8(gxHi, gxLo, pkChunk(b, UDIM + e0, GXW), a);
    }
}

// ---------------------------------------------------------------------------
// pred = h @ fc^T + fc_b (+ first-max argmax). Grid 16, block handles 16 rows.
// ---------------------------------------------------------------------------
__global__ __launch_bounds__(256) void fc_argmax(
    const short8* __restrict__ hHi, const short8* __restrict__ hLo,
    const short8* __restrict__ fcH, const short8* __restrict__ fcL,
    const float* __restrict__ fc_b, float* __restrict__ pred,
    int* __restrict__ idx) {
    __shared__ float sP[16][129];
    int tid = threadIdx.x, lane = tid & 63, wave = tid >> 6;
    int fm = blockIdx.x;
    const short8* ah = hHi + (size_t)fm * 32 * 64 + lane;
    const short8* al = hLo + (size_t)fm * 32 * 64 + lane;
    int n0 = 2 * wave, n1 = 2 * wave + 1;
    const short8* w0h = fcH + (size_t)n0 * 32 * 64 + lane;
    const short8* w0l = fcL + (size_t)n0 * 32 * 64 + lane;
    const short8* w1h = fcH + (size_t)n1 * 32 * 64 + lane;
    const short8* w1l = fcL + (size_t)n1 * 32 * 64 + lane;
    f32x4 a0 = {0,0,0,0}, a1 = {0,0,0,0};
    for (int kt = 0; kt < 32; kt++) {
        size_t o = (size_t)kt * 64;
        short8 AH = ah[o], AL = al[o];
        short8 W0H = w0h[o], W0L = w0l[o], W1H = w1h[o], W1L = w1l[o];
        MFMA(a0, AH, W0H); MFMA(a1, AH, W1H);
        MFMA(a0, AH, W0L); MFMA(a1, AH, W1L);
        MFMA(a0, AL, W0H); MFMA(a1, AL, W1H);
    }
    int cn = lane & 15, rsub = (lane >> 4) << 2;
#pragma unroll
    for (int j = 0; j < 4; j++) {
        sP[rsub + j][n0 * 16 + cn] = a0[j] + fc_b[n0 * 16 + cn];
        sP[rsub + j][n1 * 16 + cn] = a1[j] + fc_b[n1 * 16 + cn];
    }
    __syncthreads();
    {
        int row = tid >> 4, c0 = (tid & 15) * 8;
        float* pr = pred + (size_t)(fm * 16 + row) * VOUTD;
#pragma unroll
        for (int j = 0; j < 8; j++) pr[c0 + j] = sP[row][c0 + j];
    }
    if (tid < 16) {
        float v = sP[tid][0];
        int bi = 0;
        for (int j = 1; j < VOUTD; j++) {
            float w = sP[tid][j];
            if (w > v) { v = w; bi = j; }
        }
        idx[fm * 16 + tid] = bi;
    }
}

// ---------------------------------------------------------------------------
extern "C" void kernel_launch(void* const* d_in, const int* in_sizes, int n_in,
                              void* d_out, int out_size, void* d_ws, size_t ws_size,
                              hipStream_t stream) {
    const float* x       = (const float*)d_in[0];
    const int*   x_len   = (const int*)d_in[1];
    const float* enc_Wih = (const float*)d_in[2];
    const float* enc_Whh = (const float*)d_in[3];
    const float* enc_bih = (const float*)d_in[4];
    const float* enc_bhh = (const float*)d_in[5];
    const float* dec_Wih = (const float*)d_in[6];
    const float* dec_Whh = (const float*)d_in[7];
    const float* dec_bih = (const float*)d_in[8];
    const float* dec_bhh = (const float*)d_in[9];
    const float* o2h_W   = (const float*)d_in[10];
    const float* o2h_b   = (const float*)d_in[11];
    const float* fc_W    = (const float*)d_in[12];
    const float* fc_b    = (const float*)d_in[13];
    const float* W1_W    = (const float*)d_in[14];
    const float* W1_b    = (const float*)d_in[15];
    const float* W2_W    = (const float*)d_in[16];
    const float* W2_b    = (const float*)d_in[17];
    const float* V_W     = (const float*)d_in[18];
    const float* V_b     = (const float*)d_in[19];
    float* out = (float*)d_out;

    char* p = (char*)d_ws;
    auto alloc = [&](size_t bytes) -> char* {
        char* q = p;
        p += (bytes + 255) & ~(size_t)255;
        return q;
    };
    // ~221 MB total
    float* hAF  = (float*)alloc((size_t)BATCH * UDIM * 4);
    float* hBF  = (float*)alloc((size_t)BATCH * UDIM * 4);
    short* hAH  = (short*)alloc((size_t)BATCH * UDIM * 2);
    short* hAL  = (short*)alloc((size_t)BATCH * UDIM * 2);
    short* hBH  = (short*)alloc((size_t)BATCH * UDIM * 2);
    short* hBL  = (short*)alloc((size_t)BATCH * UDIM * 2);
    float* tmp2 = (float*)alloc((size_t)BATCH * UDIM * 4);
    short* gxHi = (short*)alloc((size_t)BATCH * GXW * 2);
    short* gxLo = (short*)alloc((size_t)BATCH * GXW * 2);
    short* encAHi = (short*)alloc((size_t)BATCH * SLEN * UDIM * 2);
    short* encALo = (short*)alloc((size_t)BATCH * SLEN * UDIM * 2);
    float* encProjF = (float*)alloc((size_t)BATCH * SLEN * UDIM * 4);
    float* gihBuf = (float*)alloc((size_t)8 * BATCH * U3 * 4);  // 24 MB chunk
    short* eWihH = (short*)alloc((size_t)U3 * VIND * 2);
    short* eWihL = (short*)alloc((size_t)U3 * VIND * 2);
    short* eWrH = (short*)alloc((size_t)UDIM * UDIM * 2);
    short* eWrL = (short*)alloc((size_t)UDIM * UDIM * 2);
    short* eWzH = (short*)alloc((size_t)UDIM * UDIM * 2);
    short* eWzL = (short*)alloc((size_t)UDIM * UDIM * 2);
    short* eWnH = (short*)alloc((size_t)UDIM * UDIM * 2);
    short* eWnL = (short*)alloc((size_t)UDIM * UDIM * 2);
    short* dWrH = (short*)alloc((size_t)UDIM * 2560 * 2);
    short* dWrL = (short*)alloc((size_t)UDIM * 2560 * 2);
    short* dWzH = (short*)alloc((size_t)UDIM * 2560 * 2);
    short* dWzL = (short*)alloc((size_t)UDIM * 2560 * 2);
    short* dWnhH = (short*)alloc((size_t)UDIM * UDIM * 2);
    short* dWnhL = (short*)alloc((size_t)UDIM * UDIM * 2);
    short* dWniH = (short*)alloc((size_t)UDIM * GXW * 2);
    short* dWniL = (short*)alloc((size_t)UDIM * GXW * 2);
    short* w1Hi = (short*)alloc((size_t)UDIM * UDIM * 2);
    short* w1Lo = (short*)alloc((size_t)UDIM * UDIM * 2);
    short* w2Hi = (short*)alloc((size_t)UDIM * UDIM * 2);
    short* w2Lo = (short*)alloc((size_t)UDIM * UDIM * 2);
    short* fcHi = (short*)alloc((size_t)VOUTD * UDIM * 2);
    short* fcLo = (short*)alloc((size_t)VOUTD * UDIM * 2);
    short* xHi  = (short*)alloc((size_t)SLEN * BATCH * VIND * 2);
    short* xLo  = (short*)alloc((size_t)SLEN * BATCH * VIND * 2);
    int*   idx  = (int*)alloc(BATCH * 4);

    init_kernel<<<(BATCH * UDIM + 255) / 256, 256, 0, stream>>>(hAF, hAH, hAL, out, idx);

    auto packP = [&](const float* src, int rowOff, int K, short* Hi, short* Lo, int R) {
        int chunks = R * K / 8;
        pack_split2<<<(chunks + 255) / 256, 256, 0, stream>>>(src, rowOff, K, Hi, Lo, chunks);
    };
    auto packC = [&](const float* sA, int KA, int offA, const float* sB, int KB, int offB,
                     short* Hi, short* Lo, int R) {
        int chunks = R * (KA + KB) / 8;
        pack_cat<<<(chunks + 255) / 256, 256, 0, stream>>>(sA, KA, offA, sB, KB, offB, Hi, Lo, chunks);
    };
    packP(enc_Wih, 0, VIND, eWihH, eWihL, U3);
    packP(enc_Whh, 0, UDIM, eWrH, eWrL, UDIM);
    packP(enc_Whh, UDIM, UDIM, eWzH, eWzL, UDIM);
    packP(enc_Whh, 2 * UDIM, UDIM, eWnH, eWnL, UDIM);
    packC(dec_Whh, UDIM, 0,    dec_Wih, GXW, 0,    dWrH, dWrL, UDIM);
    packC(dec_Whh, UDIM, UDIM, dec_Wih, GXW, UDIM, dWzH, dWzL, UDIM);
    packP(dec_Whh, 2 * UDIM, UDIM, dWnhH, dWnhL, UDIM);
    packP(dec_Wih, 2 * UDIM, GXW, dWniH, dWniL, UDIM);
    packP(W1_W, 0, UDIM, w1Hi, w1Lo, UDIM);
    packP(W2_W, 0, UDIM, w2Hi, w2Lo, UDIM);
    packP(fc_W, 0, UDIM, fcHi, fcLo, VOUTD);
    packP(x, 0, VIND, xHi, xLo, SLEN * BATCH);  // rows r = t*256 + b

    // ---- encoder: 8 chunks of (GIH chunk-GEMM + 8 fused GRU steps) ----
    float* hcF = hAF; float* hnF = hBF;
    short *hcH = hAH, *hcL = hAL, *hnH = hBH, *hnL = hBL;
    for (int c = 0; c < 8; c++) {
        // gi chunk: rows [2048c, 2048(c+1)) of x @ enc_Wih^T -> [2048, 3072]
        gemm_sp3<<<dim3(32, 48), 256, 0, stream>>>(
            (const short8*)xHi + (size_t)c * 128 * 4 * 64,
            (const short8*)xLo + (size_t)c * 128 * 4 * 64,
            (const short8*)eWihH, (const short8*)eWihL,
            nullptr, gihBuf, VIND / 32, U3);
        for (int tt = 0; tt < 8; tt++) {
            int t = c * 8 + tt;
            enc_gru<<<dim3(64, 4), 256, 0, stream>>>(
                (const short8*)hcH, (const short8*)hcL,
                (const short8*)eWrH, (const short8*)eWrL,
                (const short8*)eWzH, (const short8*)eWzL,
                (const short8*)eWnH, (const short8*)eWnL,
                gihBuf, enc_bih, enc_bhh, hcF, hnF, hnH, hnL,
                encAHi, encALo, x_len, t);
            { float* tf = hcF; hcF = hnF; hnF = tf; }
            { short* th = hcH; hcH = hnH; hnH = th; th = hcL; hcL = hnL; hnL = th; }
        }
    }

    // ---- enc_proj = enc_out @ W1^T + W1_b (fp32; A-tile XCD-local grid) ----
    gemm_sp3<<<dim3(SLEN * BATCH / 64, UDIM / 64), 256, 0, stream>>>(
        (const short8*)encAHi, (const short8*)encALo,
        (const short8*)w1Hi, (const short8*)w1Lo,
        W1_b, encProjF, UDIM / 32, UDIM);

    // ---- greedy decode: 24 steps x 4 dispatches ----
    for (int st = 0; st < TDEC - 1; st++) {
        gemm_bm32<<<dim3(BATCH / 32, UDIM / 64), 256, 0, stream>>>(
            (const short8*)hcH, (const short8*)hcL,
            (const short8*)w2Hi, (const short8*)w2Lo,
            W2_b, tmp2, UDIM / 32, UDIM);
        attn_ctx<<<BATCH, 256, 0, stream>>>(
            encProjF, encAHi, encALo, tmp2, V_W, V_b, o2h_W, o2h_b, idx, gxHi, gxLo);
        dec_gru<<<dim3(64, 4), 256, 0, stream>>>(
            (const short8*)hcH, (const short8*)hcL,
            (const short8*)gxHi, (const short8*)gxLo,
            (const short8*)dWrH, (const short8*)dWrL,
            (const short8*)dWzH, (const short8*)dWzL,
            (const short8*)dWnhH, (const short8*)dWnhL,
            (const short8*)dWniH, (const short8*)dWniL,
            dec_bih, dec_bhh, hcF, hnF, hnH, hnL);
        float* pred = out + (size_t)(1 + st) * BATCH * VOUTD;
        fc_argmax<<<16, 256, 0, stream>>>(
            (const short8*)hnH, (const short8*)hnL,
            (const short8*)fcHi, (const short8*)fcLo,
            fc_b, pred, idx);
        { float* tf = hcF; hcF = hnF; hnF = tf; }
        { short* th = hcH; hcH = hnH; hnH = th; th = hcL; hcL = hnL; hnL = th; }
    }
}

// Round 9
// 4623.795 us; speedup vs baseline: 2.7099x; 1.2262x over previous
//
#include <hip/hip_runtime.h>
#include <math.h>

#define SLEN 64
#define BATCH 256
#define VIND 128
#define VOUTD 128
#define UDIM 1024
#define EDIM 512
#define TDEC 25
#define GXW 1536
#define U3 3072
#define NSEG 12

typedef __attribute__((ext_vector_type(8))) short short8;
typedef __attribute__((ext_vector_type(4))) float f32x4;

#define MFMA(acc, A, B) acc = __builtin_amdgcn_mfma_f32_16x16x32_bf16((A), (B), (acc), 0, 0, 0)

__device__ __forceinline__ float sigm(float x) { return 1.f / (1.f + expf(-x)); }

// fast tanh for the attention score path only (err ~1e-6)
__device__ __forceinline__ float tanhf_fast(float x) {
    float ax = fabsf(x);
    float e = __expf(-2.f * ax);
    float t = (1.f - e) / (1.f + e);
    return copysignf(t, x);
}

__device__ __forceinline__ short f2bf(float f) {
    unsigned u = __float_as_uint(f);
    u += 0x7FFF + ((u >> 16) & 1);
    return (short)(u >> 16);
}
__device__ __forceinline__ float bf2f(short h) {
    return __uint_as_float(((unsigned)(unsigned short)h) << 16);
}

// fragment-major packed layout for operand X[R][K]:
// chunk(r,k) holds X[r][k..k+8); lane = (r&15) + 16*((k>>3)&3)
__device__ __forceinline__ size_t pkChunk(int r, int k, int K) {
    return ((size_t)(r >> 4) * (K >> 5) + (k >> 5)) * 64 + ((r & 15) + 16 * ((k >> 3) & 3));
}

union S8 { short s[8]; short8 v; };

__device__ __forceinline__ void writeSplit8(short* Hi, short* Lo, size_t chunk,
                                            const float* vals) {
    S8 h, l;
#pragma unroll
    for (int j = 0; j < 8; j++) {
        short hb = f2bf(vals[j]);
        h.s[j] = hb;
        l.s[j] = f2bf(vals[j] - bf2f(hb));
    }
    ((short8*)Hi)[chunk] = h.v;
    ((short8*)Lo)[chunk] = l.v;
}

// ---------------------------------------------------------------------------
__global__ void init_kernel(float* __restrict__ h0, short* __restrict__ hpHi,
                            short* __restrict__ hpLo, float* __restrict__ out0,
                            int* __restrict__ idx) {
    int i = blockIdx.x * 256 + threadIdx.x;
    if (i < BATCH * UDIM) { h0[i] = 0.f; hpHi[i] = 0; hpLo[i] = 0; }
    if (i < BATCH * VOUTD) out0[i] = ((i & (VOUTD - 1)) == 0) ? 1.f : 0.f;
    if (i < BATCH) idx[i] = 0;
}

// ---------------------------------------------------------------------------
// All weight/input packing in ONE kernel: segment table passed by value.
// Segment covers rows of [A | B] concatenated along K (B optional).
// ---------------------------------------------------------------------------
struct PackSeg {
    const float* sA; const float* sB;
    short* Hi; short* Lo;
    int KA, KB, offA, offB, chunkStart;
};
struct PackArgs { PackSeg s[NSEG]; };

__global__ void pack_all(PackArgs pa, int total) {
    int gid = blockIdx.x * 256 + threadIdx.x;
    if (gid >= total) return;
    int si = 0;
#pragma unroll
    for (int i = 1; i < NSEG; i++) si = (gid >= pa.s[i].chunkStart) ? i : si;
    PackSeg sg = pa.s[si];
    int local = gid - sg.chunkStart;
    int K = sg.KA + sg.KB;
    int cpr = K >> 3;
    int r = local / cpr, k0 = (local - r * cpr) * 8;
    const float* src = (k0 < sg.KA)
        ? sg.sA + (size_t)(sg.offA + r) * sg.KA + k0
        : sg.sB + (size_t)(sg.offB + r) * sg.KB + (k0 - sg.KA);
    float v[8];
#pragma unroll
    for (int j = 0; j < 8; j++) v[j] = src[j];
    writeSplit8(sg.Hi, sg.Lo, pkChunk(r, k0, K), v);
}

// ---------------------------------------------------------------------------
// Split-bf16 3-pass MFMA GEMM, BM=64 x BN=128 block (4 waves of 32x64).
// Grid (M/64, N/128); same-A blocks land on one XCD (gridDim.x % 8 == 0).
// ---------------------------------------------------------------------------
__global__ __launch_bounds__(256) void gemm_w(
    const short8* __restrict__ Ahi, const short8* __restrict__ Alo,
    const short8* __restrict__ Whi, const short8* __restrict__ Wlo,
    const float* __restrict__ bias, float* __restrict__ C,
    int KT, int N) {
    int tid = threadIdx.x, lane = tid & 63, wave = tid >> 6;
    int m16 = blockIdx.x * 4 + (wave & 1) * 2;
    int nb = blockIdx.y * 8 + (wave >> 1) * 4;  // 4 n16-tiles per wave
    const short8* a0h = Ahi + (size_t)m16 * KT * 64 + lane;
    const short8* a1h = a0h + (size_t)KT * 64;
    const short8* a0l = Alo + (size_t)m16 * KT * 64 + lane;
    const short8* a1l = a0l + (size_t)KT * 64;
    const short8* w0h = Whi + (size_t)(nb + 0) * KT * 64 + lane;
    const short8* w1h = Whi + (size_t)(nb + 1) * KT * 64 + lane;
    const short8* w2h = Whi + (size_t)(nb + 2) * KT * 64 + lane;
    const short8* w3h = Whi + (size_t)(nb + 3) * KT * 64 + lane;
    const short8* w0l = Wlo + (size_t)(nb + 0) * KT * 64 + lane;
    const short8* w1l = Wlo + (size_t)(nb + 1) * KT * 64 + lane;
    const short8* w2l = Wlo + (size_t)(nb + 2) * KT * 64 + lane;
    const short8* w3l = Wlo + (size_t)(nb + 3) * KT * 64 + lane;
    f32x4 acc0[4] = {}, acc1[4] = {};

    for (int kt = 0; kt < KT; kt++) {
        size_t o = (size_t)kt * 64;
        short8 A0H = a0h[o], A1H = a1h[o], A0L = a0l[o], A1L = a1l[o];
        short8 WH0 = w0h[o], WL0 = w0l[o];
        MFMA(acc0[0], A0H, WH0); MFMA(acc1[0], A1H, WH0);
        MFMA(acc0[0], A0H, WL0); MFMA(acc1[0], A1H, WL0);
        MFMA(acc0[0], A0L, WH0); MFMA(acc1[0], A1L, WH0);
        short8 WH1 = w1h[o], WL1 = w1l[o];
        MFMA(acc0[1], A0H, WH1); MFMA(acc1[1], A1H, WH1);
        MFMA(acc0[1], A0H, WL1); MFMA(acc1[1], A1H, WL1);
        MFMA(acc0[1], A0L, WH1); MFMA(acc1[1], A1L, WH1);
        short8 WH2 = w2h[o], WL2 = w2l[o];
        MFMA(acc0[2], A0H, WH2); MFMA(acc1[2], A1H, WH2);
        MFMA(acc0[2], A0H, WL2); MFMA(acc1[2], A1H, WL2);
        MFMA(acc0[2], A0L, WH2); MFMA(acc1[2], A1L, WH2);
        short8 WH3 = w3h[o], WL3 = w3l[o];
        MFMA(acc0[3], A0H, WH3); MFMA(acc1[3], A1H, WH3);
        MFMA(acc0[3], A0H, WL3); MFMA(acc1[3], A1H, WL3);
        MFMA(acc0[3], A0L, WH3); MFMA(acc1[3], A1L, WH3);
    }
    int rsub = (lane >> 4) * 4, cn = lane & 15;
    int row0 = (m16 + 0) * 16 + rsub;
    int row1 = (m16 + 1) * 16 + rsub;
#pragma unroll
    for (int j = 0; j < 4; j++) {
        int col = (nb + j) * 16 + cn;
        float bb = bias ? bias[col] : 0.f;
#pragma unroll
        for (int r = 0; r < 4; r++) {
            C[(size_t)(row0 + r) * N + col] = acc0[j][r] + bb;
            C[(size_t)(row1 + r) * N + col] = acc1[j][r] + bb;
        }
    }
}

// ---------------------------------------------------------------------------
// BM=32 GEMM for the pre-loop tmp2. Grid (M/32, N/64).
// ---------------------------------------------------------------------------
__global__ __launch_bounds__(256) void gemm_bm32(
    const short8* __restrict__ Ahi, const short8* __restrict__ Alo,
    const short8* __restrict__ Whi, const short8* __restrict__ Wlo,
    const float* __restrict__ bias, float* __restrict__ C,
    int KT, int N) {
    int tid = threadIdx.x, lane = tid & 63, wave = tid >> 6;
    int m16 = blockIdx.x * 2 + (wave & 1);
    int n16 = blockIdx.y * 4 + (wave >> 1) * 2;
    const short8* ah = Ahi + (size_t)m16 * KT * 64 + lane;
    const short8* al = Alo + (size_t)m16 * KT * 64 + lane;
    const short8* w0h = Whi + (size_t)n16 * KT * 64 + lane;
    const short8* w1h = w0h + (size_t)KT * 64;
    const short8* w0l = Wlo + (size_t)n16 * KT * 64 + lane;
    const short8* w1l = w0l + (size_t)KT * 64;
    f32x4 a0 = {0,0,0,0}, a1 = {0,0,0,0};
    for (int kt = 0; kt < KT; kt++) {
        size_t o = (size_t)kt * 64;
        short8 AH = ah[o], AL = al[o];
        short8 W0H = w0h[o], W0L = w0l[o], W1H = w1h[o], W1L = w1l[o];
        MFMA(a0, AH, W0H); MFMA(a1, AH, W1H);
        MFMA(a0, AH, W0L); MFMA(a1, AH, W1L);
        MFMA(a0, AL, W0H); MFMA(a1, AL, W1H);
    }
    int rsub = (lane >> 4) * 4, cn = lane & 15;
    float b0 = bias ? bias[(n16 + 0) * 16 + cn] : 0.f;
    float b1 = bias ? bias[(n16 + 1) * 16 + cn] : 0.f;
#pragma unroll
    for (int r = 0; r < 4; r++) {
        int row = m16 * 16 + rsub + r;
        C[(size_t)row * N + (n16 + 0) * 16 + cn] = a0[r] + b0;
        C[(size_t)row * N + (n16 + 1) * 16 + cn] = a1[r] + b1;
    }
}

// ---------------------------------------------------------------------------
// Encoder fused GRU step (proven in R8). Grid (64 g, 4 y).
// ---------------------------------------------------------------------------
__global__ __launch_bounds__(256) void enc_gru(
    const short8* __restrict__ hinH8, const short8* __restrict__ hinL8,
    const short8* __restrict__ WrH, const short8* __restrict__ WrL,
    const short8* __restrict__ WzH, const short8* __restrict__ WzL,
    const short8* __restrict__ WnH, const short8* __restrict__ WnL,
    const float* __restrict__ gi,
    const float* __restrict__ bih, const float* __restrict__ bhh,
    const float* __restrict__ hinF, float* __restrict__ houtF,
    short* __restrict__ hoH, short* __restrict__ hoL,
    short* __restrict__ eaHi, short* __restrict__ eaLo,
    const int* __restrict__ x_len, int t) {
    __shared__ float sHo[4][16][16];
    __shared__ float sEo[4][16][16];
    int tid = threadIdx.x, lane = tid & 63, wave = tid >> 6;
    int g = blockIdx.x;
    int m16 = blockIdx.y * 4 + wave;
    const short8* ah = hinH8 + (size_t)m16 * 32 * 64 + lane;
    const short8* al = hinL8 + (size_t)m16 * 32 * 64 + lane;
    const short8* wrh = WrH + (size_t)g * 32 * 64 + lane;
    const short8* wrl = WrL + (size_t)g * 32 * 64 + lane;
    const short8* wzh = WzH + (size_t)g * 32 * 64 + lane;
    const short8* wzl = WzL + (size_t)g * 32 * 64 + lane;
    const short8* wnh = WnH + (size_t)g * 32 * 64 + lane;
    const short8* wnl = WnL + (size_t)g * 32 * 64 + lane;
    f32x4 ar = {0,0,0,0}, az = {0,0,0,0}, anh = {0,0,0,0};
    for (int kt = 0; kt < 32; kt++) {
        size_t o = (size_t)kt * 64;
        short8 AH = ah[o], AL = al[o];
        short8 RH = wrh[o], RL = wrl[o], ZH = wzh[o], ZL = wzl[o];
        short8 NH = wnh[o], NL = wnl[o];
        MFMA(ar, AH, RH); MFMA(az, AH, ZH); MFMA(anh, AH, NH);
        MFMA(ar, AH, RL); MFMA(az, AH, ZL); MFMA(anh, AH, NL);
        MFMA(ar, AL, RH); MFMA(az, AL, ZH); MFMA(anh, AL, NH);
    }
    int cu = g * 16 + (lane & 15);
    int rsub = (lane >> 4) << 2;
    int r0 = m16 * 16 + rsub;
    float b_r = bih[cu] + bhh[cu];
    float b_z = bih[UDIM + cu] + bhh[UDIM + cu];
    float b_nh = bhh[2 * UDIM + cu];
    float b_ni = bih[2 * UDIM + cu];
    int growLocal = (t & 7) * 256;
#pragma unroll
    for (int j = 0; j < 4; j++) {
        int b = r0 + j;
        const float* gr = gi + (size_t)(growLocal + b) * U3;
        float rg = sigm(ar[j] + gr[cu] + b_r);
        float zg = sigm(az[j] + gr[UDIM + cu] + b_z);
        float nn = tanhf(gr[2 * UDIM + cu] + b_ni + rg * (anh[j] + b_nh));
        float hp = hinF[(size_t)b * UDIM + cu];
        float hv = (1.f - zg) * nn + zg * hp;
        bool msk = t < x_len[b];
        float ho = msk ? hv : hp;
        houtF[(size_t)b * UDIM + cu] = ho;
        sHo[wave][rsub + j][lane & 15] = ho;
        sEo[wave][rsub + j][lane & 15] = msk ? hv : 0.f;
    }
    __syncthreads();
    if (lane < 32) {
        int rr = lane >> 1, oct = lane & 1;
        int brow = m16 * 16 + rr;
        int u0 = g * 16 + oct * 8;
        float v[8];
#pragma unroll
        for (int j = 0; j < 8; j++) v[j] = sHo[wave][rr][oct * 8 + j];
        writeSplit8(hoH, hoL, pkChunk(brow, u0, UDIM), v);
#pragma unroll
        for (int j = 0; j < 8; j++) v[j] = sEo[wave][rr][oct * 8 + j];
        writeSplit8(eaHi, eaLo, pkChunk(brow * SLEN + t, u0, UDIM), v);
    }
}

// ---------------------------------------------------------------------------
// Decoder fused GRU step (proven in R8). Grid (64, 4).
// ---------------------------------------------------------------------------
__global__ __launch_bounds__(256) void dec_gru(
    const short8* __restrict__ hinH8, const short8* __restrict__ hinL8,
    const short8* __restrict__ gxH8, const short8* __restrict__ gxL8,
    const short8* __restrict__ WrH, const short8* __restrict__ WrL,
    const short8* __restrict__ WzH, const short8* __restrict__ WzL,
    const short8* __restrict__ WnhH, const short8* __restrict__ WnhL,
    const short8* __restrict__ WniH, const short8* __restrict__ WniL,
    const float* __restrict__ bih, const float* __restrict__ bhh,
    const float* __restrict__ hinF, float* __restrict__ houtF,
    short* __restrict__ hoH, short* __restrict__ hoL) {
    __shared__ float sHo[4][16][16];
    int tid = threadIdx.x, lane = tid & 63, wave = tid >> 6;
    int g = blockIdx.x;
    int m16 = blockIdx.y * 4 + wave;
    const short8* ah = hinH8 + (size_t)m16 * 32 * 64 + lane;
    const short8* al = hinL8 + (size_t)m16 * 32 * 64 + lane;
    const short8* gxh = gxH8 + (size_t)m16 * 48 * 64 + lane;
    const short8* gxl = gxL8 + (size_t)m16 * 48 * 64 + lane;
    const short8* wrh = WrH + (size_t)g * 80 * 64 + lane;
    const short8* wrl = WrL + (size_t)g * 80 * 64 + lane;
    const short8* wzh = WzH + (size_t)g * 80 * 64 + lane;
    const short8* wzl = WzL + (size_t)g * 80 * 64 + lane;
    const short8* wnh = WnhH + (size_t)g * 32 * 64 + lane;
    const short8* wnl = WnhL + (size_t)g * 32 * 64 + lane;
    const short8* wih = WniH + (size_t)g * 48 * 64 + lane;
    const short8* wil = WniL + (size_t)g * 48 * 64 + lane;
    f32x4 ar = {0,0,0,0}, az = {0,0,0,0}, anh = {0,0,0,0}, ani = {0,0,0,0};
    for (int kt = 0; kt < 32; kt++) {
        size_t o = (size_t)kt * 64;
        short8 AH = ah[o], AL = al[o];
        short8 RH = wrh[o], RL = wrl[o], ZH = wzh[o], ZL = wzl[o];
        short8 NH = wnh[o], NL = wnl[o];
        MFMA(ar, AH, RH); MFMA(az, AH, ZH); MFMA(anh, AH, NH);
        MFMA(ar, AH, RL); MFMA(az, AH, ZL); MFMA(anh, AH, NL);
        MFMA(ar, AL, RH); MFMA(az, AL, ZH); MFMA(anh, AL, NH);
    }
    for (int kt = 0; kt < 48; kt++) {
        size_t o = (size_t)kt * 64;
        size_t ow = (size_t)(32 + kt) * 64;
        short8 AH = gxh[o], AL = gxl[o];
        short8 RH = wrh[ow], RL = wrl[ow], ZH = wzh[ow], ZL = wzl[ow];
        short8 IH = wih[o], IL = wil[o];
        MFMA(ar, AH, RH); MFMA(az, AH, ZH); MFMA(ani, AH, IH);
        MFMA(ar, AH, RL); MFMA(az, AH, ZL); MFMA(ani, AH, IL);
        MFMA(ar, AL, RH); MFMA(az, AL, ZH); MFMA(ani, AL, IH);
    }
    int cu = g * 16 + (lane & 15);
    int rsub = (lane >> 4) << 2;
    int r0 = m16 * 16 + rsub;
    float b_r = bih[cu] + bhh[cu];
    float b_z = bih[UDIM + cu] + bhh[UDIM + cu];
    float b_nh = bhh[2 * UDIM + cu];
    float b_ni = bih[2 * UDIM + cu];
#pragma unroll
    for (int j = 0; j < 4; j++) {
        int b = r0 + j;
        float rg = sigm(ar[j] + b_r);
        float zg = sigm(az[j] + b_z);
        float nn = tanhf(ani[j] + b_ni + rg * (anh[j] + b_nh));
        float hp = hinF[(size_t)b * UDIM + cu];
        float hv = (1.f - zg) * nn + zg * hp;
        houtF[(size_t)b * UDIM + cu] = hv;
        sHo[wave][rsub + j][lane & 15] = hv;
    }
    __syncthreads();
    if (lane < 32) {
        int rr = lane >> 1, oct = lane & 1;
        int brow = m16 * 16 + rr;
        int u0 = g * 16 + oct * 8;
        float v[8];
#pragma unroll
        for (int j = 0; j < 8; j++) v[j] = sHo[wave][rr][oct * 8 + j];
        writeSplit8(hoH, hoL, pkChunk(brow, u0, UDIM), v);
    }
}

// ---------------------------------------------------------------------------
// Attention + ctx + emb -> gx split-pack. Score pass uses fast tanh.
// ---------------------------------------------------------------------------
__global__ __launch_bounds__(256) void attn_ctx(
    const float* __restrict__ encProj,
    const short* __restrict__ eaHi, const short* __restrict__ eaLo,
    const float* __restrict__ tmp2, const float* __restrict__ V_W,
    const float* __restrict__ V_b,
    const float* __restrict__ o2h_W, const float* __restrict__ o2h_b,
    const int* __restrict__ idx, short* __restrict__ gxHi, short* __restrict__ gxLo) {
    int b = blockIdx.x;
    int tid = threadIdx.x, lane = tid & 63, wave = tid >> 6;
    __shared__ float s_t2[UDIM];
    __shared__ float s_v[UDIM];
    __shared__ float s_attn[SLEN];
    for (int u = tid; u < UDIM; u += 256) {
        s_t2[u] = tmp2[(size_t)b * UDIM + u];
        s_v[u] = V_W[u];
    }
    __syncthreads();
    for (int s = wave; s < SLEN; s += 4) {
        const float4* ep4 = (const float4*)(encProj + ((size_t)b * SLEN + s) * UDIM);
        float p = 0.f;
        for (int u4 = lane; u4 < UDIM / 4; u4 += 64) {
            float4 e = ep4[u4];
            int u = 4 * u4;
            p += tanhf_fast(e.x + s_t2[u]) * s_v[u] +
                 tanhf_fast(e.y + s_t2[u + 1]) * s_v[u + 1] +
                 tanhf_fast(e.z + s_t2[u + 2]) * s_v[u + 2] +
                 tanhf_fast(e.w + s_t2[u + 3]) * s_v[u + 3];
        }
#pragma unroll
        for (int off = 32; off > 0; off >>= 1) p += __shfl_xor(p, off);
        if (lane == 0) s_attn[s] = p + V_b[0];
    }
    __syncthreads();
    if (tid < 64) {
        float v = s_attn[tid];
        float mx = v;
#pragma unroll
        for (int off = 32; off > 0; off >>= 1) mx = fmaxf(mx, __shfl_xor(mx, off));
        float e = expf(v - mx);
        float sum = e;
#pragma unroll
        for (int off = 32; off > 0; off >>= 1) sum += __shfl_xor(sum, off);
        s_attn[tid] = e / sum;
    }
    __syncthreads();
    if (tid < 128) {
        int u0 = tid * 8;
        float a[8] = {0, 0, 0, 0, 0, 0, 0, 0};
        const short8* hi8 = (const short8*)eaHi;
        const short8* lo8 = (const short8*)eaLo;
        int lanePart = 16 * ((u0 >> 3) & 3);
        int colPart = u0 >> 5;
        for (int s = 0; s < SLEN; s++) {
            int r = b * SLEN + s;
            size_t ch = ((size_t)(r >> 4) * (UDIM >> 5) + colPart) * 64 + (r & 15) + lanePart;
            S8 h, l;
            h.v = hi8[ch];
            l.v = lo8[ch];
            float w = s_attn[s];
#pragma unroll
            for (int j = 0; j < 8; j++) a[j] += w * (bf2f(h.s[j]) + bf2f(l.s[j]));
        }
        writeSplit8(gxHi, gxLo, pkChunk(b, u0, GXW), a);
    } else if (tid < 192) {
        int e0 = (tid - 128) * 8;
        int ib = idx[b];
        float a[8];
#pragma unroll
        for (int j = 0; j < 8; j++)
            a[j] = o2h_W[(size_t)(e0 + j) * VOUTD + ib] + o2h_b[e0 + j];
        writeSplit8(gxHi, gxLo, pkChunk(b, UDIM + e0, GXW), a);
    }
}

// ---------------------------------------------------------------------------
// Merged: pred=h@fc^T+b + first-max argmax (blocks 0..15) AND
// tmp2=h@W2^T+b for the next step (blocks 16..143). Both read fresh h.
// ---------------------------------------------------------------------------
__global__ __launch_bounds__(256) void fcw2(
    const short8* __restrict__ hHi, const short8* __restrict__ hLo,
    const short8* __restrict__ fcH, const short8* __restrict__ fcL,
    const float* __restrict__ fc_b, float* __restrict__ pred,
    int* __restrict__ idx,
    const short8* __restrict__ w2H, const short8* __restrict__ w2L,
    const float* __restrict__ W2_b, float* __restrict__ tmp2) {
    __shared__ float sP[16][129];
    int tid = threadIdx.x, lane = tid & 63, wave = tid >> 6;
    if (blockIdx.x < 16) {
        int fm = blockIdx.x;
        const short8* ah = hHi + (size_t)fm * 32 * 64 + lane;
        const short8* al = hLo + (size_t)fm * 32 * 64 + lane;
        int n0 = 2 * wave, n1 = 2 * wave + 1;
        const short8* w0h = fcH + (size_t)n0 * 32 * 64 + lane;
        const short8* w0l = fcL + (size_t)n0 * 32 * 64 + lane;
        const short8* w1h = fcH + (size_t)n1 * 32 * 64 + lane;
        const short8* w1l = fcL + (size_t)n1 * 32 * 64 + lane;
        f32x4 a0 = {0,0,0,0}, a1 = {0,0,0,0};
        for (int kt = 0; kt < 32; kt++) {
            size_t o = (size_t)kt * 64;
            short8 AH = ah[o], AL = al[o];
            short8 W0H = w0h[o], W0L = w0l[o], W1H = w1h[o], W1L = w1l[o];
            MFMA(a0, AH, W0H); MFMA(a1, AH, W1H);
            MFMA(a0, AH, W0L); MFMA(a1, AH, W1L);
            MFMA(a0, AL, W0H); MFMA(a1, AL, W1H);
        }
        int cn = lane & 15, rsub = (lane >> 4) << 2;
#pragma unroll
        for (int j = 0; j < 4; j++) {
            sP[rsub + j][n0 * 16 + cn] = a0[j] + fc_b[n0 * 16 + cn];
            sP[rsub + j][n1 * 16 + cn] = a1[j] + fc_b[n1 * 16 + cn];
        }
        __syncthreads();
        {
            int row = tid >> 4, c0 = (tid & 15) * 8;
            float* pr = pred + (size_t)(fm * 16 + row) * VOUTD;
#pragma unroll
            for (int j = 0; j < 8; j++) pr[c0 + j] = sP[row][c0 + j];
        }
        if (tid < 16) {
            float v = sP[tid][0];
            int bi = 0;
            for (int j = 1; j < VOUTD; j++) {
                float w = sP[tid][j];
                if (w > v) { v = w; bi = j; }
            }
            idx[fm * 16 + tid] = bi;
        }
    } else {
        int lin = blockIdx.x - 16;       // 0..127
        int bx = lin & 7, by = lin >> 3; // bm32 grid (8, 16)
        int m16 = bx * 2 + (wave & 1);
        int n16 = by * 4 + (wave >> 1) * 2;
        const short8* ah = hHi + (size_t)m16 * 32 * 64 + lane;
        const short8* al = hLo + (size_t)m16 * 32 * 64 + lane;
        const short8* w0h = w2H + (size_t)n16 * 32 * 64 + lane;
        const short8* w1h = w0h + (size_t)32 * 64;
        const short8* w0l = w2L + (size_t)n16 * 32 * 64 + lane;
        const short8* w1l = w0l + (size_t)32 * 64;
        f32x4 a0 = {0,0,0,0}, a1 = {0,0,0,0};
        for (int kt = 0; kt < 32; kt++) {
            size_t o = (size_t)kt * 64;
            short8 AH = ah[o], AL = al[o];
            short8 W0H = w0h[o], W0L = w0l[o], W1H = w1h[o], W1L = w1l[o];
            MFMA(a0, AH, W0H); MFMA(a1, AH, W1H);
            MFMA(a0, AH, W0L); MFMA(a1, AH, W1L);
            MFMA(a0, AL, W0H); MFMA(a1, AL, W1H);
        }
        int rsub = (lane >> 4) * 4, cn = lane & 15;
        float b0 = W2_b[(n16 + 0) * 16 + cn];
        float b1 = W2_b[(n16 + 1) * 16 + cn];
#pragma unroll
        for (int r = 0; r < 4; r++) {
            int row = m16 * 16 + rsub + r;
            tmp2[(size_t)row * UDIM + (n16 + 0) * 16 + cn] = a0[r] + b0;
            tmp2[(size_t)row * UDIM + (n16 + 1) * 16 + cn] = a1[r] + b1;
        }
    }
}

// ---------------------------------------------------------------------------
extern "C" void kernel_launch(void* const* d_in, const int* in_sizes, int n_in,
                              void* d_out, int out_size, void* d_ws, size_t ws_size,
                              hipStream_t stream) {
    const float* x       = (const float*)d_in[0];
    const int*   x_len   = (const int*)d_in[1];
    const float* enc_Wih = (const float*)d_in[2];
    const float* enc_Whh = (const float*)d_in[3];
    const float* enc_bih = (const float*)d_in[4];
    const float* enc_bhh = (const float*)d_in[5];
    const float* dec_Wih = (const float*)d_in[6];
    const float* dec_Whh = (const float*)d_in[7];
    const float* dec_bih = (const float*)d_in[8];
    const float* dec_bhh = (const float*)d_in[9];
    const float* o2h_W   = (const float*)d_in[10];
    const float* o2h_b   = (const float*)d_in[11];
    const float* fc_W    = (const float*)d_in[12];
    const float* fc_b    = (const float*)d_in[13];
    const float* W1_W    = (const float*)d_in[14];
    const float* W1_b    = (const float*)d_in[15];
    const float* W2_W    = (const float*)d_in[16];
    const float* W2_b    = (const float*)d_in[17];
    const float* V_W     = (const float*)d_in[18];
    const float* V_b     = (const float*)d_in[19];
    float* out = (float*)d_out;

    char* p = (char*)d_ws;
    auto alloc = [&](size_t bytes) -> char* {
        char* q = p;
        p += (bytes + 255) & ~(size_t)255;
        return q;
    };
    float* hAF  = (float*)alloc((size_t)BATCH * UDIM * 4);
    float* hBF  = (float*)alloc((size_t)BATCH * UDIM * 4);
    short* hAH  = (short*)alloc((size_t)BATCH * UDIM * 2);
    short* hAL  = (short*)alloc((size_t)BATCH * UDIM * 2);
    short* hBH  = (short*)alloc((size_t)BATCH * UDIM * 2);
    short* hBL  = (short*)alloc((size_t)BATCH * UDIM * 2);
    float* tmp2 = (float*)alloc((size_t)BATCH * UDIM * 4);
    short* gxHi = (short*)alloc((size_t)BATCH * GXW * 2);
    short* gxLo = (short*)alloc((size_t)BATCH * GXW * 2);
    short* encAHi = (short*)alloc((size_t)BATCH * SLEN * UDIM * 2);
    short* encALo = (short*)alloc((size_t)BATCH * SLEN * UDIM * 2);
    float* encProjF = (float*)alloc((size_t)BATCH * SLEN * UDIM * 4);
    float* gihBuf = (float*)alloc((size_t)8 * BATCH * U3 * 4);
    short* eWihH = (short*)alloc((size_t)U3 * VIND * 2);
    short* eWihL = (short*)alloc((size_t)U3 * VIND * 2);
    short* eWrH = (short*)alloc((size_t)UDIM * UDIM * 2);
    short* eWrL = (short*)alloc((size_t)UDIM * UDIM * 2);
    short* eWzH = (short*)alloc((size_t)UDIM * UDIM * 2);
    short* eWzL = (short*)alloc((size_t)UDIM * UDIM * 2);
    short* eWnH = (short*)alloc((size_t)UDIM * UDIM * 2);
    short* eWnL = (short*)alloc((size_t)UDIM * UDIM * 2);
    short* dWrH = (short*)alloc((size_t)UDIM * 2560 * 2);
    short* dWrL = (short*)alloc((size_t)UDIM * 2560 * 2);
    short* dWzH = (short*)alloc((size_t)UDIM * 2560 * 2);
    short* dWzL = (short*)alloc((size_t)UDIM * 2560 * 2);
    short* dWnhH = (short*)alloc((size_t)UDIM * UDIM * 2);
    short* dWnhL = (short*)alloc((size_t)UDIM * UDIM * 2);
    short* dWniH = (short*)alloc((size_t)UDIM * GXW * 2);
    short* dWniL = (short*)alloc((size_t)UDIM * GXW * 2);
    short* w1Hi = (short*)alloc((size_t)UDIM * UDIM * 2);
    short* w1Lo = (short*)alloc((size_t)UDIM * UDIM * 2);
    short* w2Hi = (short*)alloc((size_t)UDIM * UDIM * 2);
    short* w2Lo = (short*)alloc((size_t)UDIM * UDIM * 2);
    short* fcHi = (short*)alloc((size_t)VOUTD * UDIM * 2);
    short* fcLo = (short*)alloc((size_t)VOUTD * UDIM * 2);
    short* xHi  = (short*)alloc((size_t)SLEN * BATCH * VIND * 2);
    short* xLo  = (short*)alloc((size_t)SLEN * BATCH * VIND * 2);
    int*   idx  = (int*)alloc(BATCH * 4);

    init_kernel<<<(BATCH * UDIM + 255) / 256, 256, 0, stream>>>(hAF, hAH, hAL, out, idx);

    // ---- single packing kernel for all weights + x ----
    {
        PackArgs pa;
        int cs = 0, n = 0;
        auto seg = [&](const float* sA, int KA, int offA, const float* sB, int KB,
                       int offB, short* Hi, short* Lo, int R) {
            pa.s[n] = {sA, sB, Hi, Lo, KA, KB, offA, offB, cs};
            cs += R * (KA + KB) / 8;
            n++;
        };
        seg(enc_Wih, VIND, 0, nullptr, 0, 0, eWihH, eWihL, U3);
        seg(enc_Whh, UDIM, 0, nullptr, 0, 0, eWrH, eWrL, UDIM);
        seg(enc_Whh, UDIM, UDIM, nullptr, 0, 0, eWzH, eWzL, UDIM);
        seg(enc_Whh, UDIM, 2 * UDIM, nullptr, 0, 0, eWnH, eWnL, UDIM);
        seg(dec_Whh, UDIM, 0, dec_Wih, GXW, 0, dWrH, dWrL, UDIM);
        seg(dec_Whh, UDIM, UDIM, dec_Wih, GXW, UDIM, dWzH, dWzL, UDIM);
        seg(dec_Whh, UDIM, 2 * UDIM, nullptr, 0, 0, dWnhH, dWnhL, UDIM);
        seg(dec_Wih, GXW, 2 * UDIM, nullptr, 0, 0, dWniH, dWniL, UDIM);
        seg(W1_W, UDIM, 0, nullptr, 0, 0, w1Hi, w1Lo, UDIM);
        seg(W2_W, UDIM, 0, nullptr, 0, 0, w2Hi, w2Lo, UDIM);
        seg(fc_W, UDIM, 0, nullptr, 0, 0, fcHi, fcLo, VOUTD);
        seg(x, VIND, 0, nullptr, 0, 0, xHi, xLo, SLEN * BATCH);
        pack_all<<<(cs + 255) / 256, 256, 0, stream>>>(pa, cs);
    }

    // ---- encoder: 8 chunks of (gi chunk-GEMM + 8 fused GRU steps) ----
    float* hcF = hAF; float* hnF = hBF;
    short *hcH = hAH, *hcL = hAL, *hnH = hBH, *hnL = hBL;
    for (int c = 0; c < 8; c++) {
        gemm_w<<<dim3(32, 24), 256, 0, stream>>>(
            (const short8*)xHi + (size_t)c * 128 * 4 * 64,
            (const short8*)xLo + (size_t)c * 128 * 4 * 64,
            (const short8*)eWihH, (const short8*)eWihL,
            nullptr, gihBuf, VIND / 32, U3);
        for (int tt = 0; tt < 8; tt++) {
            int t = c * 8 + tt;
            enc_gru<<<dim3(64, 4), 256, 0, stream>>>(
                (const short8*)hcH, (const short8*)hcL,
                (const short8*)eWrH, (const short8*)eWrL,
                (const short8*)eWzH, (const short8*)eWzL,
                (const short8*)eWnH, (const short8*)eWnL,
                gihBuf, enc_bih, enc_bhh, hcF, hnF, hnH, hnL,
                encAHi, encALo, x_len, t);
            { float* tf = hcF; hcF = hnF; hnF = tf; }
            { short* th = hcH; hcH = hnH; hnH = th; th = hcL; hcL = hnL; hnL = th; }
        }
    }

    // ---- enc_proj = enc_out @ W1^T + W1_b (fp32, BN=128 blocks) ----
    gemm_w<<<dim3(SLEN * BATCH / 64, UDIM / 128), 256, 0, stream>>>(
        (const short8*)encAHi, (const short8*)encALo,
        (const short8*)w1Hi, (const short8*)w1Lo,
        W1_b, encProjF, UDIM / 32, UDIM);

    // ---- initial tmp2 from encoder hidden ----
    gemm_bm32<<<dim3(BATCH / 32, UDIM / 64), 256, 0, stream>>>(
        (const short8*)hcH, (const short8*)hcL,
        (const short8*)w2Hi, (const short8*)w2Lo,
        W2_b, tmp2, UDIM / 32, UDIM);

    // ---- greedy decode: 24 steps x 3 dispatches ----
    for (int st = 0; st < TDEC - 1; st++) {
        attn_ctx<<<BATCH, 256, 0, stream>>>(
            encProjF, encAHi, encALo, tmp2, V_W, V_b, o2h_W, o2h_b, idx, gxHi, gxLo);
        dec_gru<<<dim3(64, 4), 256, 0, stream>>>(
            (const short8*)hcH, (const short8*)hcL,
            (const short8*)gxHi, (const short8*)gxLo,
            (const short8*)dWrH, (const short8*)dWrL,
            (const short8*)dWzH, (const short8*)dWzL,
            (const short8*)dWnhH, (const short8*)dWnhL,
            (const short8*)dWniH, (const short8*)dWniL,
            dec_bih, dec_bhh, hcF, hnF, hnH, hnL);
        float* pred = out + (size_t)(1 + st) * BATCH * VOUTD;
        fcw2<<<144, 256, 0, stream>>>(
            (const short8*)hnH, (const short8*)hnL,
            (const short8*)fcHi, (const short8*)fcLo,
            fc_b, pred, idx,
            (const short8*)w2Hi, (const short8*)w2Lo, W2_b, tmp2);
        { float* tf = hcF; hcF = hnF; hnF = tf; }
        { short* th = hcH; hcH = hnH; hnH = th; th = hcL; hcL = hnL; hnL = th; }
    }
}

// Round 10
// 4165.705 us; speedup vs baseline: 3.0078x; 1.1100x over previous
//
#include <hip/hip_runtime.h>
#include <math.h>

#define SLEN 64
#define BATCH 256
#define VIND 128
#define VOUTD 128
#define UDIM 1024
#define EDIM 512
#define TDEC 25
#define GXW 1536
#define U3 3072
#define NSEG 12

typedef __attribute__((ext_vector_type(8))) short short8;
typedef __attribute__((ext_vector_type(4))) float f32x4;

#define MFMA(acc, A, B) acc = __builtin_amdgcn_mfma_f32_16x16x32_bf16((A), (B), (acc), 0, 0, 0)

__device__ __forceinline__ float sigm(float x) { return 1.f / (1.f + expf(-x)); }

// fast tanh for the attention score path only (err ~1e-6)
__device__ __forceinline__ float tanhf_fast(float x) {
    float ax = fabsf(x);
    float e = __expf(-2.f * ax);
    float t = (1.f - e) / (1.f + e);
    return copysignf(t, x);
}

__device__ __forceinline__ short f2bf(float f) {
    unsigned u = __float_as_uint(f);
    u += 0x7FFF + ((u >> 16) & 1);
    return (short)(u >> 16);
}
__device__ __forceinline__ float bf2f(short h) {
    return __uint_as_float(((unsigned)(unsigned short)h) << 16);
}

// fragment-major packed layout for operand X[R][K]:
// chunk(r,k) holds X[r][k..k+8); lane = (r&15) + 16*((k>>3)&3)
__device__ __forceinline__ size_t pkChunk(int r, int k, int K) {
    return ((size_t)(r >> 4) * (K >> 5) + (k >> 5)) * 64 + ((r & 15) + 16 * ((k >> 3) & 3));
}

union S8 { short s[8]; short8 v; };

__device__ __forceinline__ void writeSplit8(short* Hi, short* Lo, size_t chunk,
                                            const float* vals) {
    S8 h, l;
#pragma unroll
    for (int j = 0; j < 8; j++) {
        short hb = f2bf(vals[j]);
        h.s[j] = hb;
        l.s[j] = f2bf(vals[j] - bf2f(hb));
    }
    ((short8*)Hi)[chunk] = h.v;
    ((short8*)Lo)[chunk] = l.v;
}

// ---------------------------------------------------------------------------
__global__ void init_kernel(float* __restrict__ h0, short* __restrict__ hpHi,
                            short* __restrict__ hpLo, float* __restrict__ out0,
                            int* __restrict__ idx) {
    int i = blockIdx.x * 256 + threadIdx.x;
    if (i < BATCH * UDIM) { h0[i] = 0.f; hpHi[i] = 0; hpLo[i] = 0; }
    if (i < BATCH * VOUTD) out0[i] = ((i & (VOUTD - 1)) == 0) ? 1.f : 0.f;
    if (i < BATCH) idx[i] = 0;
}

// ---------------------------------------------------------------------------
// All weight/input packing in ONE kernel: segment table passed by value.
// ---------------------------------------------------------------------------
struct PackSeg {
    const float* sA; const float* sB;
    short* Hi; short* Lo;
    int KA, KB, offA, offB, chunkStart;
};
struct PackArgs { PackSeg s[NSEG]; };

__global__ void pack_all(PackArgs pa, int total) {
    int gid = blockIdx.x * 256 + threadIdx.x;
    if (gid >= total) return;
    int si = 0;
#pragma unroll
    for (int i = 1; i < NSEG; i++) si = (gid >= pa.s[i].chunkStart) ? i : si;
    PackSeg sg = pa.s[si];
    int local = gid - sg.chunkStart;
    int K = sg.KA + sg.KB;
    int cpr = K >> 3;
    int r = local / cpr, k0 = (local - r * cpr) * 8;
    const float* src = (k0 < sg.KA)
        ? sg.sA + (size_t)(sg.offA + r) * sg.KA + k0
        : sg.sB + (size_t)(sg.offB + r) * sg.KB + (k0 - sg.KA);
    float v[8];
#pragma unroll
    for (int j = 0; j < 8; j++) v[j] = src[j];
    writeSplit8(sg.Hi, sg.Lo, pkChunk(r, k0, K), v);
}

// ---------------------------------------------------------------------------
// Split-bf16 3-pass MFMA GEMM, BM=64 x BN=128 block (4 waves of 32x64).
// ---------------------------------------------------------------------------
__global__ __launch_bounds__(256) void gemm_w(
    const short8* __restrict__ Ahi, const short8* __restrict__ Alo,
    const short8* __restrict__ Whi, const short8* __restrict__ Wlo,
    const float* __restrict__ bias, float* __restrict__ C,
    int KT, int N) {
    int tid = threadIdx.x, lane = tid & 63, wave = tid >> 6;
    int m16 = blockIdx.x * 4 + (wave & 1) * 2;
    int nb = blockIdx.y * 8 + (wave >> 1) * 4;
    const short8* a0h = Ahi + (size_t)m16 * KT * 64 + lane;
    const short8* a1h = a0h + (size_t)KT * 64;
    const short8* a0l = Alo + (size_t)m16 * KT * 64 + lane;
    const short8* a1l = a0l + (size_t)KT * 64;
    const short8* w0h = Whi + (size_t)(nb + 0) * KT * 64 + lane;
    const short8* w1h = Whi + (size_t)(nb + 1) * KT * 64 + lane;
    const short8* w2h = Whi + (size_t)(nb + 2) * KT * 64 + lane;
    const short8* w3h = Whi + (size_t)(nb + 3) * KT * 64 + lane;
    const short8* w0l = Wlo + (size_t)(nb + 0) * KT * 64 + lane;
    const short8* w1l = Wlo + (size_t)(nb + 1) * KT * 64 + lane;
    const short8* w2l = Wlo + (size_t)(nb + 2) * KT * 64 + lane;
    const short8* w3l = Wlo + (size_t)(nb + 3) * KT * 64 + lane;
    f32x4 acc0[4] = {}, acc1[4] = {};

    for (int kt = 0; kt < KT; kt++) {
        size_t o = (size_t)kt * 64;
        short8 A0H = a0h[o], A1H = a1h[o], A0L = a0l[o], A1L = a1l[o];
        short8 WH0 = w0h[o], WL0 = w0l[o];
        MFMA(acc0[0], A0H, WH0); MFMA(acc1[0], A1H, WH0);
        MFMA(acc0[0], A0H, WL0); MFMA(acc1[0], A1H, WL0);
        MFMA(acc0[0], A0L, WH0); MFMA(acc1[0], A1L, WH0);
        short8 WH1 = w1h[o], WL1 = w1l[o];
        MFMA(acc0[1], A0H, WH1); MFMA(acc1[1], A1H, WH1);
        MFMA(acc0[1], A0H, WL1); MFMA(acc1[1], A1H, WL1);
        MFMA(acc0[1], A0L, WH1); MFMA(acc1[1], A1L, WH1);
        short8 WH2 = w2h[o], WL2 = w2l[o];
        MFMA(acc0[2], A0H, WH2); MFMA(acc1[2], A1H, WH2);
        MFMA(acc0[2], A0H, WL2); MFMA(acc1[2], A1H, WL2);
        MFMA(acc0[2], A0L, WH2); MFMA(acc1[2], A1L, WH2);
        short8 WH3 = w3h[o], WL3 = w3l[o];
        MFMA(acc0[3], A0H, WH3); MFMA(acc1[3], A1H, WH3);
        MFMA(acc0[3], A0H, WL3); MFMA(acc1[3], A1H, WL3);
        MFMA(acc0[3], A0L, WH3); MFMA(acc1[3], A1L, WH3);
    }
    int rsub = (lane >> 4) * 4, cn = lane & 15;
    int row0 = (m16 + 0) * 16 + rsub;
    int row1 = (m16 + 1) * 16 + rsub;
#pragma unroll
    for (int j = 0; j < 4; j++) {
        int col = (nb + j) * 16 + cn;
        float bb = bias ? bias[col] : 0.f;
#pragma unroll
        for (int r = 0; r < 4; r++) {
            C[(size_t)(row0 + r) * N + col] = acc0[j][r] + bb;
            C[(size_t)(row1 + r) * N + col] = acc1[j][r] + bb;
        }
    }
}

// ---------------------------------------------------------------------------
// BM=32 GEMM for the pre-loop tmp2. Grid (M/32, N/64).
// ---------------------------------------------------------------------------
__global__ __launch_bounds__(256) void gemm_bm32(
    const short8* __restrict__ Ahi, const short8* __restrict__ Alo,
    const short8* __restrict__ Whi, const short8* __restrict__ Wlo,
    const float* __restrict__ bias, float* __restrict__ C,
    int KT, int N) {
    int tid = threadIdx.x, lane = tid & 63, wave = tid >> 6;
    int m16 = blockIdx.x * 2 + (wave & 1);
    int n16 = blockIdx.y * 4 + (wave >> 1) * 2;
    const short8* ah = Ahi + (size_t)m16 * KT * 64 + lane;
    const short8* al = Alo + (size_t)m16 * KT * 64 + lane;
    const short8* w0h = Whi + (size_t)n16 * KT * 64 + lane;
    const short8* w1h = w0h + (size_t)KT * 64;
    const short8* w0l = Wlo + (size_t)n16 * KT * 64 + lane;
    const short8* w1l = w0l + (size_t)KT * 64;
    f32x4 a0 = {0,0,0,0}, a1 = {0,0,0,0};
    for (int kt = 0; kt < KT; kt++) {
        size_t o = (size_t)kt * 64;
        short8 AH = ah[o], AL = al[o];
        short8 W0H = w0h[o], W0L = w0l[o], W1H = w1h[o], W1L = w1l[o];
        MFMA(a0, AH, W0H); MFMA(a1, AH, W1H);
        MFMA(a0, AH, W0L); MFMA(a1, AH, W1L);
        MFMA(a0, AL, W0H); MFMA(a1, AL, W1H);
    }
    int rsub = (lane >> 4) * 4, cn = lane & 15;
    float b0 = bias ? bias[(n16 + 0) * 16 + cn] : 0.f;
    float b1 = bias ? bias[(n16 + 1) * 16 + cn] : 0.f;
#pragma unroll
    for (int r = 0; r < 4; r++) {
        int row = m16 * 16 + rsub + r;
        C[(size_t)row * N + (n16 + 0) * 16 + cn] = a0[r] + b0;
        C[(size_t)row * N + (n16 + 1) * 16 + cn] = a1[r] + b1;
    }
}

// ---------------------------------------------------------------------------
// Encoder GRU step, plane-per-wave: block = 3 waves (r, z, nh); grid (64, 16)
// = 1024 blocks = 12 waves/CU. Same math as R9's proven enc_gru.
// ---------------------------------------------------------------------------
__global__ __launch_bounds__(192) void enc_gru3(
    const short8* __restrict__ hinH8, const short8* __restrict__ hinL8,
    const short8* __restrict__ WrH, const short8* __restrict__ WrL,
    const short8* __restrict__ WzH, const short8* __restrict__ WzL,
    const short8* __restrict__ WnH, const short8* __restrict__ WnL,
    const float* __restrict__ gi,
    const float* __restrict__ bih, const float* __restrict__ bhh,
    const float* __restrict__ hinF, float* __restrict__ houtF,
    short* __restrict__ hoH, short* __restrict__ hoL,
    short* __restrict__ eaHi, short* __restrict__ eaLo,
    const int* __restrict__ x_len, int t) {
    __shared__ float sC[3][16][16];
    __shared__ float sHo[16][16];
    __shared__ float sEo[16][16];
    int tid = threadIdx.x, lane = tid & 63, wave = tid >> 6;
    int g = blockIdx.x;
    int m16 = blockIdx.y;
    const short8* ah = hinH8 + (size_t)m16 * 32 * 64 + lane;
    const short8* al = hinL8 + (size_t)m16 * 32 * 64 + lane;
    const short8* wh;
    const short8* wl;
    if (wave == 0) { wh = WrH + (size_t)g * 32 * 64 + lane; wl = WrL + (size_t)g * 32 * 64 + lane; }
    else if (wave == 1) { wh = WzH + (size_t)g * 32 * 64 + lane; wl = WzL + (size_t)g * 32 * 64 + lane; }
    else { wh = WnH + (size_t)g * 32 * 64 + lane; wl = WnL + (size_t)g * 32 * 64 + lane; }
    f32x4 acc = {0, 0, 0, 0};
    for (int kt = 0; kt < 32; kt++) {
        size_t o = (size_t)kt * 64;
        short8 AH = ah[o], AL = al[o];
        short8 WH = wh[o], WL = wl[o];
        MFMA(acc, AH, WH);
        MFMA(acc, AH, WL);
        MFMA(acc, AL, WH);
    }
    {
        int rsub = (lane >> 4) << 2, cn = lane & 15;
#pragma unroll
        for (int j = 0; j < 4; j++) sC[wave][rsub + j][cn] = acc[j];
    }
    __syncthreads();
    if (wave == 0) {
        int cu = g * 16 + (lane & 15);
        int rsub = (lane >> 4) << 2;
        float b_r = bih[cu] + bhh[cu];
        float b_z = bih[UDIM + cu] + bhh[UDIM + cu];
        float b_nh = bhh[2 * UDIM + cu];
        float b_ni = bih[2 * UDIM + cu];
        int growLocal = (t & 7) * 256;
#pragma unroll
        for (int j = 0; j < 4; j++) {
            int b = m16 * 16 + rsub + j;
            const float* gr = gi + (size_t)(growLocal + b) * U3;
            float rg = sigm(sC[0][rsub + j][lane & 15] + gr[cu] + b_r);
            float zg = sigm(sC[1][rsub + j][lane & 15] + gr[UDIM + cu] + b_z);
            float nn = tanhf(gr[2 * UDIM + cu] + b_ni +
                             rg * (sC[2][rsub + j][lane & 15] + b_nh));
            float hp = hinF[(size_t)b * UDIM + cu];
            float hv = (1.f - zg) * nn + zg * hp;
            bool msk = t < x_len[b];
            float ho = msk ? hv : hp;
            houtF[(size_t)b * UDIM + cu] = ho;
            sHo[rsub + j][lane & 15] = ho;
            sEo[rsub + j][lane & 15] = msk ? hv : 0.f;
        }
    }
    __syncthreads();
    if (wave == 1 && lane < 32) {
        int rr = lane >> 1, oct = lane & 1;
        int brow = m16 * 16 + rr;
        int u0 = g * 16 + oct * 8;
        float v[8];
#pragma unroll
        for (int j = 0; j < 8; j++) v[j] = sHo[rr][oct * 8 + j];
        writeSplit8(hoH, hoL, pkChunk(brow, u0, UDIM), v);
#pragma unroll
        for (int j = 0; j < 8; j++) v[j] = sEo[rr][oct * 8 + j];
        writeSplit8(eaHi, eaLo, pkChunk(brow * SLEN + t, u0, UDIM), v);
    }
}

// ---------------------------------------------------------------------------
// Decoder GRU step, plane-per-wave: wave0=r(80kt), wave1=z(80kt),
// wave2=nh(32kt h)+ni(48kt gx). Grid (64, 16) = 1024 blocks.
// ---------------------------------------------------------------------------
__global__ __launch_bounds__(192) void dec_gru3(
    const short8* __restrict__ hinH8, const short8* __restrict__ hinL8,
    const short8* __restrict__ gxH8, const short8* __restrict__ gxL8,
    const short8* __restrict__ WrH, const short8* __restrict__ WrL,
    const short8* __restrict__ WzH, const short8* __restrict__ WzL,
    const short8* __restrict__ WnhH, const short8* __restrict__ WnhL,
    const short8* __restrict__ WniH, const short8* __restrict__ WniL,
    const float* __restrict__ bih, const float* __restrict__ bhh,
    const float* __restrict__ hinF, float* __restrict__ houtF,
    short* __restrict__ hoH, short* __restrict__ hoL) {
    __shared__ float sC[4][16][16];
    __shared__ float sHo[16][16];
    int tid = threadIdx.x, lane = tid & 63, wave = tid >> 6;
    int g = blockIdx.x;
    int m16 = blockIdx.y;
    const short8* ah = hinH8 + (size_t)m16 * 32 * 64 + lane;
    const short8* al = hinL8 + (size_t)m16 * 32 * 64 + lane;
    const short8* gxh = gxH8 + (size_t)m16 * 48 * 64 + lane;
    const short8* gxl = gxL8 + (size_t)m16 * 48 * 64 + lane;
    // weight streams: waves 0/1 use contiguous 80-kt plane; wave 2 uses
    // nh (32 kt) for the h-part and ni (48 kt) for the gx-part.
    const short8 *whA, *wlA, *whB, *wlB;
    if (wave == 0) {
        whA = WrH + (size_t)g * 80 * 64 + lane; wlA = WrL + (size_t)g * 80 * 64 + lane;
        whB = whA + 32 * 64; wlB = wlA + 32 * 64;
    } else if (wave == 1) {
        whA = WzH + (size_t)g * 80 * 64 + lane; wlA = WzL + (size_t)g * 80 * 64 + lane;
        whB = whA + 32 * 64; wlB = wlA + 32 * 64;
    } else {
        whA = WnhH + (size_t)g * 32 * 64 + lane; wlA = WnhL + (size_t)g * 32 * 64 + lane;
        whB = WniH + (size_t)g * 48 * 64 + lane; wlB = WniL + (size_t)g * 48 * 64 + lane;
    }
    f32x4 accA = {0,0,0,0}, accB = {0,0,0,0};
    for (int kt = 0; kt < 32; kt++) {
        size_t o = (size_t)kt * 64;
        short8 AH = ah[o], AL = al[o];
        short8 WH = whA[o], WL = wlA[o];
        MFMA(accA, AH, WH);
        MFMA(accA, AH, WL);
        MFMA(accA, AL, WH);
    }
    for (int kt = 0; kt < 48; kt++) {
        size_t o = (size_t)kt * 64;
        short8 AH = gxh[o], AL = gxl[o];
        short8 WH = whB[o], WL = wlB[o];
        MFMA(accB, AH, WH);
        MFMA(accB, AH, WL);
        MFMA(accB, AL, WH);
    }
    {
        int rsub = (lane >> 4) << 2, cn = lane & 15;
        if (wave < 2) {
#pragma unroll
            for (int j = 0; j < 4; j++) sC[wave][rsub + j][cn] = accA[j] + accB[j];
        } else {
#pragma unroll
            for (int j = 0; j < 4; j++) {
                sC[2][rsub + j][cn] = accA[j];
                sC[3][rsub + j][cn] = accB[j];
            }
        }
    }
    __syncthreads();
    if (wave == 0) {
        int cu = g * 16 + (lane & 15);
        int rsub = (lane >> 4) << 2;
        float b_r = bih[cu] + bhh[cu];
        float b_z = bih[UDIM + cu] + bhh[UDIM + cu];
        float b_nh = bhh[2 * UDIM + cu];
        float b_ni = bih[2 * UDIM + cu];
#pragma unroll
        for (int j = 0; j < 4; j++) {
            int b = m16 * 16 + rsub + j;
            float rg = sigm(sC[0][rsub + j][lane & 15] + b_r);
            float zg = sigm(sC[1][rsub + j][lane & 15] + b_z);
            float nn = tanhf(sC[3][rsub + j][lane & 15] + b_ni +
                             rg * (sC[2][rsub + j][lane & 15] + b_nh));
            float hp = hinF[(size_t)b * UDIM + cu];
            float hv = (1.f - zg) * nn + zg * hp;
            houtF[(size_t)b * UDIM + cu] = hv;
            sHo[rsub + j][lane & 15] = hv;
        }
    }
    __syncthreads();
    if (wave == 1 && lane < 32) {
        int rr = lane >> 1, oct = lane & 1;
        int brow = m16 * 16 + rr;
        int u0 = g * 16 + oct * 8;
        float v[8];
#pragma unroll
        for (int j = 0; j < 8; j++) v[j] = sHo[rr][oct * 8 + j];
        writeSplit8(hoH, hoL, pkChunk(brow, u0, UDIM), v);
    }
}

// ---------------------------------------------------------------------------
// Attention + ctx + emb -> gx split-pack. Score pass uses fast tanh.
// ---------------------------------------------------------------------------
__global__ __launch_bounds__(256) void attn_ctx(
    const float* __restrict__ encProj,
    const short* __restrict__ eaHi, const short* __restrict__ eaLo,
    const float* __restrict__ tmp2, const float* __restrict__ V_W,
    const float* __restrict__ V_b,
    const float* __restrict__ o2h_W, const float* __restrict__ o2h_b,
    const int* __restrict__ idx, short* __restrict__ gxHi, short* __restrict__ gxLo) {
    int b = blockIdx.x;
    int tid = threadIdx.x, lane = tid & 63, wave = tid >> 6;
    __shared__ float s_t2[UDIM];
    __shared__ float s_v[UDIM];
    __shared__ float s_attn[SLEN];
    for (int u = tid; u < UDIM; u += 256) {
        s_t2[u] = tmp2[(size_t)b * UDIM + u];
        s_v[u] = V_W[u];
    }
    __syncthreads();
    for (int s = wave; s < SLEN; s += 4) {
        const float4* ep4 = (const float4*)(encProj + ((size_t)b * SLEN + s) * UDIM);
        float p = 0.f;
        for (int u4 = lane; u4 < UDIM / 4; u4 += 64) {
            float4 e = ep4[u4];
            int u = 4 * u4;
            p += tanhf_fast(e.x + s_t2[u]) * s_v[u] +
                 tanhf_fast(e.y + s_t2[u + 1]) * s_v[u + 1] +
                 tanhf_fast(e.z + s_t2[u + 2]) * s_v[u + 2] +
                 tanhf_fast(e.w + s_t2[u + 3]) * s_v[u + 3];
        }
#pragma unroll
        for (int off = 32; off > 0; off >>= 1) p += __shfl_xor(p, off);
        if (lane == 0) s_attn[s] = p + V_b[0];
    }
    __syncthreads();
    if (tid < 64) {
        float v = s_attn[tid];
        float mx = v;
#pragma unroll
        for (int off = 32; off > 0; off >>= 1) mx = fmaxf(mx, __shfl_xor(mx, off));
        float e = expf(v - mx);
        float sum = e;
#pragma unroll
        for (int off = 32; off > 0; off >>= 1) sum += __shfl_xor(sum, off);
        s_attn[tid] = e / sum;
    }
    __syncthreads();
    if (tid < 128) {
        int u0 = tid * 8;
        float a[8] = {0, 0, 0, 0, 0, 0, 0, 0};
        const short8* hi8 = (const short8*)eaHi;
        const short8* lo8 = (const short8*)eaLo;
        int lanePart = 16 * ((u0 >> 3) & 3);
        int colPart = u0 >> 5;
        for (int s = 0; s < SLEN; s++) {
            int r = b * SLEN + s;
            size_t ch = ((size_t)(r >> 4) * (UDIM >> 5) + colPart) * 64 + (r & 15) + lanePart;
            S8 h, l;
            h.v = hi8[ch];
            l.v = lo8[ch];
            float w = s_attn[s];
#pragma unroll
            for (int j = 0; j < 8; j++) a[j] += w * (bf2f(h.s[j]) + bf2f(l.s[j]));
        }
        writeSplit8(gxHi, gxLo, pkChunk(b, u0, GXW), a);
    } else if (tid < 192) {
        int e0 = (tid - 128) * 8;
        int ib = idx[b];
        float a[8];
#pragma unroll
        for (int j = 0; j < 8; j++)
            a[j] = o2h_W[(size_t)(e0 + j) * VOUTD + ib] + o2h_b[e0 + j];
        writeSplit8(gxHi, gxLo, pkChunk(b, UDIM + e0, GXW), a);
    }
}

// ---------------------------------------------------------------------------
// Merged: pred=h@fc^T+b + first-max argmax (blocks 0..15) AND
// tmp2=h@W2^T+b for the next step (blocks 16..143).
// ---------------------------------------------------------------------------
__global__ __launch_bounds__(256) void fcw2(
    const short8* __restrict__ hHi, const short8* __restrict__ hLo,
    const short8* __restrict__ fcH, const short8* __restrict__ fcL,
    const float* __restrict__ fc_b, float* __restrict__ pred,
    int* __restrict__ idx,
    const short8* __restrict__ w2H, const short8* __restrict__ w2L,
    const float* __restrict__ W2_b, float* __restrict__ tmp2) {
    __shared__ float sP[16][129];
    int tid = threadIdx.x, lane = tid & 63, wave = tid >> 6;
    if (blockIdx.x < 16) {
        int fm = blockIdx.x;
        const short8* ah = hHi + (size_t)fm * 32 * 64 + lane;
        const short8* al = hLo + (size_t)fm * 32 * 64 + lane;
        int n0 = 2 * wave, n1 = 2 * wave + 1;
        const short8* w0h = fcH + (size_t)n0 * 32 * 64 + lane;
        const short8* w0l = fcL + (size_t)n0 * 32 * 64 + lane;
        const short8* w1h = fcH + (size_t)n1 * 32 * 64 + lane;
        const short8* w1l = fcL + (size_t)n1 * 32 * 64 + lane;
        f32x4 a0 = {0,0,0,0}, a1 = {0,0,0,0};
        for (int kt = 0; kt < 32; kt++) {
            size_t o = (size_t)kt * 64;
            short8 AH = ah[o], AL = al[o];
            short8 W0H = w0h[o], W0L = w0l[o], W1H = w1h[o], W1L = w1l[o];
            MFMA(a0, AH, W0H); MFMA(a1, AH, W1H);
            MFMA(a0, AH, W0L); MFMA(a1, AH, W1L);
            MFMA(a0, AL, W0H); MFMA(a1, AL, W1H);
        }
        int cn = lane & 15, rsub = (lane >> 4) << 2;
#pragma unroll
        for (int j = 0; j < 4; j++) {
            sP[rsub + j][n0 * 16 + cn] = a0[j] + fc_b[n0 * 16 + cn];
            sP[rsub + j][n1 * 16 + cn] = a1[j] + fc_b[n1 * 16 + cn];
        }
        __syncthreads();
        {
            int row = tid >> 4, c0 = (tid & 15) * 8;
            float* pr = pred + (size_t)(fm * 16 + row) * VOUTD;
#pragma unroll
            for (int j = 0; j < 8; j++) pr[c0 + j] = sP[row][c0 + j];
        }
        if (tid < 16) {
            float v = sP[tid][0];
            int bi = 0;
            for (int j = 1; j < VOUTD; j++) {
                float w = sP[tid][j];
                if (w > v) { v = w; bi = j; }
            }
            idx[fm * 16 + tid] = bi;
        }
    } else {
        int lin = blockIdx.x - 16;       // 0..127
        int bx = lin & 7, by = lin >> 3; // bm32 grid (8, 16)
        int m16 = bx * 2 + (wave & 1);
        int n16 = by * 4 + (wave >> 1) * 2;
        const short8* ah = hHi + (size_t)m16 * 32 * 64 + lane;
        const short8* al = hLo + (size_t)m16 * 32 * 64 + lane;
        const short8* w0h = w2H + (size_t)n16 * 32 * 64 + lane;
        const short8* w1h = w0h + (size_t)32 * 64;
        const short8* w0l = w2L + (size_t)n16 * 32 * 64 + lane;
        const short8* w1l = w0l + (size_t)32 * 64;
        f32x4 a0 = {0,0,0,0}, a1 = {0,0,0,0};
        for (int kt = 0; kt < 32; kt++) {
            size_t o = (size_t)kt * 64;
            short8 AH = ah[o], AL = al[o];
            short8 W0H = w0h[o], W0L = w0l[o], W1H = w1h[o], W1L = w1l[o];
            MFMA(a0, AH, W0H); MFMA(a1, AH, W1H);
            MFMA(a0, AH, W0L); MFMA(a1, AH, W1L);
            MFMA(a0, AL, W0H); MFMA(a1, AL, W1H);
        }
        int rsub = (lane >> 4) * 4, cn = lane & 15;
        float b0 = W2_b[(n16 + 0) * 16 + cn];
        float b1 = W2_b[(n16 + 1) * 16 + cn];
#pragma unroll
        for (int r = 0; r < 4; r++) {
            int row = m16 * 16 + rsub + r;
            tmp2[(size_t)row * UDIM + (n16 + 0) * 16 + cn] = a0[r] + b0;
            tmp2[(size_t)row * UDIM + (n16 + 1) * 16 + cn] = a1[r] + b1;
        }
    }
}

// ---------------------------------------------------------------------------
extern "C" void kernel_launch(void* const* d_in, const int* in_sizes, int n_in,
                              void* d_out, int out_size, void* d_ws, size_t ws_size,
                              hipStream_t stream) {
    const float* x       = (const float*)d_in[0];
    const int*   x_len   = (const int*)d_in[1];
    const float* enc_Wih = (const float*)d_in[2];
    const float* enc_Whh = (const float*)d_in[3];
    const float* enc_bih = (const float*)d_in[4];
    const float* enc_bhh = (const float*)d_in[5];
    const float* dec_Wih = (const float*)d_in[6];
    const float* dec_Whh = (const float*)d_in[7];
    const float* dec_bih = (const float*)d_in[8];
    const float* dec_bhh = (const float*)d_in[9];
    const float* o2h_W   = (const float*)d_in[10];
    const float* o2h_b   = (const float*)d_in[11];
    const float* fc_W    = (const float*)d_in[12];
    const float* fc_b    = (const float*)d_in[13];
    const float* W1_W    = (const float*)d_in[14];
    const float* W1_b    = (const float*)d_in[15];
    const float* W2_W    = (const float*)d_in[16];
    const float* W2_b    = (const float*)d_in[17];
    const float* V_W     = (const float*)d_in[18];
    const float* V_b     = (const float*)d_in[19];
    float* out = (float*)d_out;

    char* p = (char*)d_ws;
    auto alloc = [&](size_t bytes) -> char* {
        char* q = p;
        p += (bytes + 255) & ~(size_t)255;
        return q;
    };
    float* hAF  = (float*)alloc((size_t)BATCH * UDIM * 4);
    float* hBF  = (float*)alloc((size_t)BATCH * UDIM * 4);
    short* hAH  = (short*)alloc((size_t)BATCH * UDIM * 2);
    short* hAL  = (short*)alloc((size_t)BATCH * UDIM * 2);
    short* hBH  = (short*)alloc((size_t)BATCH * UDIM * 2);
    short* hBL  = (short*)alloc((size_t)BATCH * UDIM * 2);
    float* tmp2 = (float*)alloc((size_t)BATCH * UDIM * 4);
    short* gxHi = (short*)alloc((size_t)BATCH * GXW * 2);
    short* gxLo = (short*)alloc((size_t)BATCH * GXW * 2);
    short* encAHi = (short*)alloc((size_t)BATCH * SLEN * UDIM * 2);
    short* encALo = (short*)alloc((size_t)BATCH * SLEN * UDIM * 2);
    float* encProjF = (float*)alloc((size_t)BATCH * SLEN * UDIM * 4);
    float* gihBuf = (float*)alloc((size_t)8 * BATCH * U3 * 4);
    short* eWihH = (short*)alloc((size_t)U3 * VIND * 2);
    short* eWihL = (short*)alloc((size_t)U3 * VIND * 2);
    short* eWrH = (short*)alloc((size_t)UDIM * UDIM * 2);
    short* eWrL = (short*)alloc((size_t)UDIM * UDIM * 2);
    short* eWzH = (short*)alloc((size_t)UDIM * UDIM * 2);
    short* eWzL = (short*)alloc((size_t)UDIM * UDIM * 2);
    short* eWnH = (short*)alloc((size_t)UDIM * UDIM * 2);
    short* eWnL = (short*)alloc((size_t)UDIM * UDIM * 2);
    short* dWrH = (short*)alloc((size_t)UDIM * 2560 * 2);
    short* dWrL = (short*)alloc((size_t)UDIM * 2560 * 2);
    short* dWzH = (short*)alloc((size_t)UDIM * 2560 * 2);
    short* dWzL = (short*)alloc((size_t)UDIM * 2560 * 2);
    short* dWnhH = (short*)alloc((size_t)UDIM * UDIM * 2);
    short* dWnhL = (short*)alloc((size_t)UDIM * UDIM * 2);
    short* dWniH = (short*)alloc((size_t)UDIM * GXW * 2);
    short* dWniL = (short*)alloc((size_t)UDIM * GXW * 2);
    short* w1Hi = (short*)alloc((size_t)UDIM * UDIM * 2);
    short* w1Lo = (short*)alloc((size_t)UDIM * UDIM * 2);
    short* w2Hi = (short*)alloc((size_t)UDIM * UDIM * 2);
    short* w2Lo = (short*)alloc((size_t)UDIM * UDIM * 2);
    short* fcHi = (short*)alloc((size_t)VOUTD * UDIM * 2);
    short* fcLo = (short*)alloc((size_t)VOUTD * UDIM * 2);
    short* xHi  = (short*)alloc((size_t)SLEN * BATCH * VIND * 2);
    short* xLo  = (short*)alloc((size_t)SLEN * BATCH * VIND * 2);
    int*   idx  = (int*)alloc(BATCH * 4);

    init_kernel<<<(BATCH * UDIM + 255) / 256, 256, 0, stream>>>(hAF, hAH, hAL, out, idx);

    // ---- single packing kernel for all weights + x ----
    {
        PackArgs pa;
        int cs = 0, n = 0;
        auto seg = [&](const float* sA, int KA, int offA, const float* sB, int KB,
                       int offB, short* Hi, short* Lo, int R) {
            pa.s[n] = {sA, sB, Hi, Lo, KA, KB, offA, offB, cs};
            cs += R * (KA + KB) / 8;
            n++;
        };
        seg(enc_Wih, VIND, 0, nullptr, 0, 0, eWihH, eWihL, U3);
        seg(enc_Whh, UDIM, 0, nullptr, 0, 0, eWrH, eWrL, UDIM);
        seg(enc_Whh, UDIM, UDIM, nullptr, 0, 0, eWzH, eWzL, UDIM);
        seg(enc_Whh, UDIM, 2 * UDIM, nullptr, 0, 0, eWnH, eWnL, UDIM);
        seg(dec_Whh, UDIM, 0, dec_Wih, GXW, 0, dWrH, dWrL, UDIM);
        seg(dec_Whh, UDIM, UDIM, dec_Wih, GXW, UDIM, dWzH, dWzL, UDIM);
        seg(dec_Whh, UDIM, 2 * UDIM, nullptr, 0, 0, dWnhH, dWnhL, UDIM);
        seg(dec_Wih, GXW, 2 * UDIM, nullptr, 0, 0, dWniH, dWniL, UDIM);
        seg(W1_W, UDIM, 0, nullptr, 0, 0, w1Hi, w1Lo, UDIM);
        seg(W2_W, UDIM, 0, nullptr, 0, 0, w2Hi, w2Lo, UDIM);
        seg(fc_W, UDIM, 0, nullptr, 0, 0, fcHi, fcLo, VOUTD);
        seg(x, VIND, 0, nullptr, 0, 0, xHi, xLo, SLEN * BATCH);
        pack_all<<<(cs + 255) / 256, 256, 0, stream>>>(pa, cs);
    }

    // ---- encoder: 8 chunks of (gi chunk-GEMM + 8 fused GRU steps) ----
    float* hcF = hAF; float* hnF = hBF;
    short *hcH = hAH, *hcL = hAL, *hnH = hBH, *hnL = hBL;
    for (int c = 0; c < 8; c++) {
        gemm_w<<<dim3(32, 24), 256, 0, stream>>>(
            (const short8*)xHi + (size_t)c * 128 * 4 * 64,
            (const short8*)xLo + (size_t)c * 128 * 4 * 64,
            (const short8*)eWihH, (const short8*)eWihL,
            nullptr, gihBuf, VIND / 32, U3);
        for (int tt = 0; tt < 8; tt++) {
            int t = c * 8 + tt;
            enc_gru3<<<dim3(64, 16), 192, 0, stream>>>(
                (const short8*)hcH, (const short8*)hcL,
                (const short8*)eWrH, (const short8*)eWrL,
                (const short8*)eWzH, (const short8*)eWzL,
                (const short8*)eWnH, (const short8*)eWnL,
                gihBuf, enc_bih, enc_bhh, hcF, hnF, hnH, hnL,
                encAHi, encALo, x_len, t);
            { float* tf = hcF; hcF = hnF; hnF = tf; }
            { short* th = hcH; hcH = hnH; hnH = th; th = hcL; hcL = hnL; hnL = th; }
        }
    }

    // ---- enc_proj = enc_out @ W1^T + W1_b (fp32, BN=128 blocks) ----
    gemm_w<<<dim3(SLEN * BATCH / 64, UDIM / 128), 256, 0, stream>>>(
        (const short8*)encAHi, (const short8*)encALo,
        (const short8*)w1Hi, (const short8*)w1Lo,
        W1_b, encProjF, UDIM / 32, UDIM);

    // ---- initial tmp2 from encoder hidden ----
    gemm_bm32<<<dim3(BATCH / 32, UDIM / 64), 256, 0, stream>>>(
        (const short8*)hcH, (const short8*)hcL,
        (const short8*)w2Hi, (const short8*)w2Lo,
        W2_b, tmp2, UDIM / 32, UDIM);

    // ---- greedy decode: 24 steps x 3 dispatches ----
    for (int st = 0; st < TDEC - 1; st++) {
        attn_ctx<<<BATCH, 256, 0, stream>>>(
            encProjF, encAHi, encALo, tmp2, V_W, V_b, o2h_W, o2h_b, idx, gxHi, gxLo);
        dec_gru3<<<dim3(64, 16), 192, 0, stream>>>(
            (const short8*)hcH, (const short8*)hcL,
            (const short8*)gxHi, (const short8*)gxLo,
            (const short8*)dWrH, (const short8*)dWrL,
            (const short8*)dWzH, (const short8*)dWzL,
            (const short8*)dWnhH, (const short8*)dWnhL,
            (const short8*)dWniH, (const short8*)dWniL,
            dec_bih, dec_bhh, hcF, hnF, hnH, hnL);
        float* pred = out + (size_t)(1 + st) * BATCH * VOUTD;
        fcw2<<<144, 256, 0, stream>>>(
            (const short8*)hnH, (const short8*)hnL,
            (const short8*)fcHi, (const short8*)fcLo,
            fc_b, pred, idx,
            (const short8*)w2Hi, (const short8*)w2Lo, W2_b, tmp2);
        { float* tf = hcF; hcF = hnF; hnF = tf; }
        { short* th = hcH; hcH = hnH; hnH = th; th = hcL; hcL = hnL; hnL = th; }
    }
}